// Round 4
// baseline (216.270 us; speedup 1.0000x reference)
//
#include <hip/hip_runtime.h>

typedef unsigned short U16;
typedef __bf16 bf16x8 __attribute__((ext_vector_type(8)));
typedef float f32x4 __attribute__((ext_vector_type(4)));
typedef float f32x16 __attribute__((ext_vector_type(16)));

__device__ inline float b2f(U16 u) {
    union { unsigned int i; float f; } v;
    v.i = ((unsigned int)u) << 16;
    return v.f;
}
__device__ inline U16 f2b(float f) {
    union { float f; unsigned int u; } v;
    v.f = f;
    unsigned int r = (v.u + 0x7fffu + ((v.u >> 16) & 1u)) >> 16;
    return (U16)r;
}

// pack two f32 -> two bf16 in one u32 (RNE, same as f2b)
__device__ inline unsigned cvt_pk(float lo, float hi) {
    unsigned d;
    asm("v_cvt_pk_bf16_f32 %0, %1, %2" : "=v"(d) : "v"(lo), "v"(hi));
    return d;
}
// swap: a[lanes 32-63] <-> b[lanes 0-31]
__device__ inline void plswap(unsigned &a, unsigned &b) {
    asm("v_permlane32_swap_b32 %0, %1" : "+v"(a), "+v"(b));
}

// async global->LDS, 16B per lane (LDS dest = wave-uniform base + lane*16)
__device__ inline void gld16(const void* g, void* l) {
    __builtin_amdgcn_global_load_lds(
        (const __attribute__((address_space(1))) void*)g,
        (__attribute__((address_space(3))) void*)l, 16, 0, 0);
}

// ------- Transpose + fp32->bf16: out[c][r] = bf16(in[r][c]), R x C /32 ------
__global__ void transpose_f2b(const float* __restrict__ in, U16* __restrict__ out,
                              int R, int C) {
    __shared__ float tile[32][33];
    int c0 = blockIdx.x * 32, r0 = blockIdx.y * 32;
    int tx = threadIdx.x, ty = threadIdx.y; // 32 x 8
#pragma unroll
    for (int i = 0; i < 32; i += 8)
        tile[ty + i][tx] = in[(size_t)(r0 + ty + i) * C + c0 + tx];
    __syncthreads();
#pragma unroll
    for (int i = 0; i < 32; i += 8)
        out[(size_t)(c0 + ty + i) * R + r0 + tx] = f2b(tile[tx][ty + i]);
}

// ------- LayerNorm: fp32 in -> bf16 out, one block (256 thr) per 1024-row ---
__global__ __launch_bounds__(256) void ln_kernel(const float* __restrict__ x,
                                                 const float* __restrict__ gamma,
                                                 const float* __restrict__ beta,
                                                 U16* __restrict__ xn) {
    int row = blockIdx.x;
    int t = threadIdx.x;
    float4 raw = ((const float4*)(x + (size_t)row * 1024))[t];
    float v[4] = { raw.x, raw.y, raw.z, raw.w };
    float s = v[0] + v[1] + v[2] + v[3];
    float s2 = v[0] * v[0] + v[1] * v[1] + v[2] * v[2] + v[3] * v[3];
#pragma unroll
    for (int off = 32; off >= 1; off >>= 1) {
        s  += __shfl_xor(s,  off);
        s2 += __shfl_xor(s2, off);
    }
    __shared__ float red[8];
    if ((t & 63) == 0) { red[(t >> 6) * 2] = s; red[(t >> 6) * 2 + 1] = s2; }
    __syncthreads();
    float S  = red[0] + red[2] + red[4] + red[6];
    float S2 = red[1] + red[3] + red[5] + red[7];
    float mu = S * (1.0f / 1024.0f);
    float var = S2 * (1.0f / 1024.0f) - mu * mu;
    float rstd = rsqrtf(var + 1e-5f);
    float4 g4 = ((const float4*)gamma)[t];
    float4 b4 = ((const float4*)beta)[t];
    ushort4 o;
    o.x = f2b((v[0] - mu) * rstd * g4.x + b4.x);
    o.y = f2b((v[1] - mu) * rstd * g4.y + b4.y);
    o.z = f2b((v[2] - mu) * rstd * g4.z + b4.z);
    o.w = f2b((v[3] - mu) * rstd * g4.w + b4.w);
    ((ushort4*)(xn + (size_t)row * 1024))[t] = o;
}

// ------ GEMM: C[M,N] = A[M,K] * Bt[N,K]^T (+fp32 bias), OutT = U16 or float -
// m97 structure: 128x128 tile, BK=32, global_load_lds width=16 staging.
// If vT != nullptr: N-tiles with n0 >= 2048 (the V third of QKV) are written
// transposed to vT[(b*16+h)*64+d][token] instead of C.
template <typename OutT>
__global__ __launch_bounds__(256) void gemm_bt(const U16* __restrict__ A,
                                               const U16* __restrict__ Bt,
                                               const float* __restrict__ bias,
                                               OutT* __restrict__ C,
                                               U16* __restrict__ vT,
                                               int M, int N, int K) {
    __shared__ __align__(16) U16 As[128 * 32];
    __shared__ __align__(16) U16 Bs[128 * 32];
    const int m0 = blockIdx.y * 128, n0 = blockIdx.x * 128;
    const int t = threadIdx.x;
    const int wave = t >> 6, lane = t & 63, l15 = lane & 15, quad = lane >> 4;
    const int wm = (wave >> 1) * 64, wn = (wave & 1) * 64;

    f32x4 acc[4][4];
#pragma unroll
    for (int i = 0; i < 4; i++)
#pragma unroll
        for (int j = 0; j < 4; j++)
            acc[i][j] = (f32x4){0.f, 0.f, 0.f, 0.f};

    const int c0i = t, c1i = 256 + t;
    const int r0 = c0i >> 2, kq0 = c0i & 3;
    const int r1 = c1i >> 2, kq1 = c1i & 3;

    for (int k0 = 0; k0 < K; k0 += 32) {
        gld16(&A[(size_t)(m0 + r0) * K + k0 + kq0 * 8], &As[c0i * 8]);
        gld16(&Bt[(size_t)(n0 + r0) * K + k0 + kq0 * 8], &Bs[c0i * 8]);
        gld16(&A[(size_t)(m0 + r1) * K + k0 + kq1 * 8], &As[c1i * 8]);
        gld16(&Bt[(size_t)(n0 + r1) * K + k0 + kq1 * 8], &Bs[c1i * 8]);
        __syncthreads();
        bf16x8 af[4], bfr[4];
#pragma unroll
        for (int i = 0; i < 4; i++)
            af[i] = *(const bf16x8*)&As[(wm + i * 16 + l15) * 32 + quad * 8];
#pragma unroll
        for (int j = 0; j < 4; j++)
            bfr[j] = *(const bf16x8*)&Bs[(wn + j * 16 + l15) * 32 + quad * 8];
#pragma unroll
        for (int i = 0; i < 4; i++)
#pragma unroll
            for (int j = 0; j < 4; j++)
                acc[i][j] = __builtin_amdgcn_mfma_f32_16x16x32_bf16(
                    af[i], bfr[j], acc[i][j], 0, 0, 0);
        __syncthreads();
    }
    if (vT && n0 >= 2048) {
#pragma unroll
        for (int i = 0; i < 4; i++) {
#pragma unroll
            for (int j = 0; j < 4; j++) {
                int col = n0 + wn + j * 16 + l15 - 2048;
                int hh = col >> 6, dd = col & 63;
                int row0 = m0 + wm + i * 16 + quad * 4;
                int bb = row0 >> 11, nn = row0 & 2047;
                ushort4 st;
                st.x = f2b(acc[i][j][0]); st.y = f2b(acc[i][j][1]);
                st.z = f2b(acc[i][j][2]); st.w = f2b(acc[i][j][3]);
                *(ushort4*)&vT[((((size_t)bb * 16) + hh) * 64 + dd) * 2048 + nn] = st;
            }
        }
        return;
    }
#pragma unroll
    for (int i = 0; i < 4; i++) {
#pragma unroll
        for (int j = 0; j < 4; j++) {
            int col = n0 + wn + j * 16 + l15;
            float bv = bias ? bias[col] : 0.0f;
#pragma unroll
            for (int r = 0; r < 4; r++) {
                int row = m0 + wm + i * 16 + quad * 4 + r;
                float val = acc[i][j][r] + bv;
                if constexpr (sizeof(OutT) == 4)
                    C[(size_t)row * N + col] = val;
                else
                    C[(size_t)row * N + col] = f2b(val);
            }
        }
    }
}

// ---- MFMA flash attention: in-register softmax (r3) + split-K x2 (r2).
//
// r3 post-mortem: in-reg softmax cut LDS traffic (attn 75->60.5us) but the
// kernel is now latency/VALU-bound: VALUBusy 50% (exp2 chain), MfmaUtil 23%,
// with only 2 waves/SIMD to overlap the serial exp2->cvt_pk->PV chain.
// Total q-work = 2048 wave-units = exactly 8 waves/CU, so >2 waves/SIMD
// REQUIRES key-splitting. r2's split-K blockers are gone now: the kernel is
// no longer LDS-BW-bound (more waves help) and LDS is 32 KB (4 blocks =
// 128 KB fits; VGPR 72 <= 128 -> 4 waves/SIMD allowed).
//
// Split-K x2: grid 1024, each block owns 16 of 32 k-tiles. Static softmax ->
// partials merge exactly: po (unnormalized fp32 O) and pl (row sums) add.
// po0 lives in d_out (dead until GEMM2 overwrites), po1+pl in ws.
//
// Structure (unchanged from r3): swapped QK^T S^T = mfma(K,Q) 32x32x16 ->
// lane-local softmax sums; P->bf16 PV B-operand via v_cvt_pk_bf16_f32 +
// v_permlane32_swap_b32, all in registers; PV: O^T = mfma(V^T, P^T).
// XCD swizzle: all blocks of one (b,h) on one XCD (FETCH 71.7 -> 12 MB).
// LDS oct swizzle: chunk (row r, slot j) fetches global oct j^(r&7);
// readers take oct o of row r from slot o^(r&7).
__global__ __launch_bounds__(256) void attn_kernel(const U16* __restrict__ qkv,
                                                   const U16* __restrict__ vT,
                                                   float* __restrict__ po0,
                                                   float* __restrict__ po1,
                                                   float* __restrict__ pl) {
    const int p = blockIdx.x;                    // 0..1023
    const int xcd = p & 7;
    const int slot = p >> 3;                     // 0..127 within XCD
    const int bh = ((slot & 3) << 3) | xcd;      // bh & 7 == XCD id
    const int r2 = slot >> 2;                    // 0..31
    const int qt = r2 & 15;                      // 16 q-tiles of 128 rows
    const int half = r2 >> 4;                    // key half: tiles [half*16, +16)
    const int b = bh >> 4, h = bh & 15;
    const int t = threadIdx.x;
    const int wave = t >> 6, lane = t & 63;
    const int l31 = lane & 31, hi = lane >> 5;
    const float sc2 = 0.125f * 1.44269504089f;  // scale * log2(e)

    __shared__ __align__(16) U16 Kt[2][64 * 64];    // [key][d-swizzled]
    __shared__ __align__(16) U16 Vt[2][64 * 64];    // [d][key-swizzled]

    const size_t base = (size_t)(b * 2048) * 3072;
    const U16* vTbh = vT + ((size_t)(b * 16 + h) * 64) * 2048;
    const int kbase = half * 16;                 // first k-tile of our half

    // Q fragments (B-operand of swapped QK^T): lane(hi,q=l31) holds
    // Q[qrow][d = s*16 + hi*8 .. +8] for k-slices s=0..3
    bf16x8 qf[4];
    {
        int qrow = qt * 128 + wave * 32 + l31;
        const U16* qp = qkv + base + (size_t)qrow * 3072 + h * 64 + hi * 8;
#pragma unroll
        for (int s = 0; s < 4; s++)
            qf[s] = *(const bf16x8*)&qp[s * 16];
    }

    float l_acc = 0.0f;
    f32x16 oacc[2];  // O^T[d][q]: d = db*32 + (reg&3)+8*(reg>>2)+4*hi, q=l31
#pragma unroll
    for (int db = 0; db < 2; db++)
#pragma unroll
        for (int r = 0; r < 16; r++)
            oacc[db][r] = 0.0f;

    // staging: chunk c -> LDS offset c*16B; row=c>>3, slot=c&7,
    // fetched global oct = slot ^ (row&7)
    const int c0 = t, c1 = 256 + t;
    const int row0 = c0 >> 3, oct0 = (c0 & 7) ^ (row0 & 7);
    const int row1 = c1 >> 3, oct1 = (c1 & 7) ^ (row1 & 7);

    // prefetch tile kbase into buf 0
    {
        int nt = kbase;
        gld16(&qkv[base + (size_t)(nt * 64 + row0) * 3072 + 1024 + h * 64 + oct0 * 8], &Kt[0][c0 * 8]);
        gld16(&qkv[base + (size_t)(nt * 64 + row1) * 3072 + 1024 + h * 64 + oct1 * 8], &Kt[0][c1 * 8]);
        gld16(&vTbh[(size_t)row0 * 2048 + nt * 64 + oct0 * 8], &Vt[0][c0 * 8]);
        gld16(&vTbh[(size_t)row1 * 2048 + nt * 64 + oct1 * 8], &Vt[0][c1 * 8]);
    }
    __syncthreads();

    for (int i = 0; i < 16; i++) {
        // ---- async prefetch of tile i+1 (wraps harmlessly at the end) ----
        {
            int nt = kbase + ((i + 1) & 15), nb = (i + 1) & 1;
            gld16(&qkv[base + (size_t)(nt * 64 + row0) * 3072 + 1024 + h * 64 + oct0 * 8], &Kt[nb][c0 * 8]);
            gld16(&qkv[base + (size_t)(nt * 64 + row1) * 3072 + 1024 + h * 64 + oct1 * 8], &Kt[nb][c1 * 8]);
            gld16(&vTbh[(size_t)row0 * 2048 + nt * 64 + oct0 * 8], &Vt[nb][c0 * 8]);
            gld16(&vTbh[(size_t)row1 * 2048 + nt * 64 + oct1 * 8], &Vt[nb][c1 * 8]);
        }
        const U16* KtC = &Kt[i & 1][0];
        const U16* VtC = &Vt[i & 1][0];

#pragma unroll
        for (int kb = 0; kb < 2; kb++) {
            // ---- K A-frags: K[key = kb*32+l31][d = s*16 + hi*8 ..+8] ----
            bf16x8 kf[4];
#pragma unroll
            for (int s = 0; s < 4; s++)
                kf[s] = *(const bf16x8*)&KtC[(kb * 32 + l31) * 64 +
                                             (((s * 2 + hi) ^ (l31 & 7)) * 8)];
            // ---- V A-frags issued early (latency under QK^T + softmax):
            //      V^T[d = db*32+l31][key = kb*32 + s*16 + hi*8 ..+8] ----
            bf16x8 vfr[2][2];
#pragma unroll
            for (int db = 0; db < 2; db++)
#pragma unroll
                for (int s = 0; s < 2; s++)
                    vfr[db][s] = *(const bf16x8*)&VtC[(db * 32 + l31) * 64 +
                                                      (((kb * 4 + s * 2 + hi) ^ (l31 & 7)) * 8)];

            // ---- QK^T: S^T[key][q] ----
            f32x16 st = {0.f, 0.f, 0.f, 0.f, 0.f, 0.f, 0.f, 0.f,
                         0.f, 0.f, 0.f, 0.f, 0.f, 0.f, 0.f, 0.f};
            __builtin_amdgcn_s_setprio(1);
#pragma unroll
            for (int s = 0; s < 4; s++)
                st = __builtin_amdgcn_mfma_f32_32x32x16_bf16(kf[s], qf[s], st, 0, 0, 0);
            __builtin_amdgcn_s_setprio(0);

            // ---- softmax (static, exp2), lane-local row sum ----
            float pe[16];
#pragma unroll
            for (int r = 0; r < 16; r++) {
                pe[r] = __builtin_amdgcn_exp2f(st[r] * sc2);
                l_acc += pe[r];
            }

            // ---- pack P^T into PV B-frags (registers only) ----
            // regs s*8 + {0..7} = keys kb*32 + s*16 + {4hi+0..3, 8+4hi+0..3};
            // after 2 swaps per slice, word e holds keys (hi*8+2e, hi*8+2e+1).
#pragma unroll
            for (int s = 0; s < 2; s++) {
                unsigned p01 = cvt_pk(pe[s * 8 + 0], pe[s * 8 + 1]);
                unsigned p23 = cvt_pk(pe[s * 8 + 2], pe[s * 8 + 3]);
                unsigned p45 = cvt_pk(pe[s * 8 + 4], pe[s * 8 + 5]);
                unsigned p67 = cvt_pk(pe[s * 8 + 6], pe[s * 8 + 7]);
                plswap(p01, p45);
                plswap(p23, p67);
                union { unsigned u[4]; bf16x8 v; } pw;
                pw.u[0] = p01; pw.u[1] = p23; pw.u[2] = p45; pw.u[3] = p67;
                // ---- PV: O^T += V^T x P^T ----
                __builtin_amdgcn_s_setprio(1);
#pragma unroll
                for (int db = 0; db < 2; db++)
                    oacc[db] = __builtin_amdgcn_mfma_f32_32x32x16_bf16(
                        vfr[db][s], pw.v, oacc[db], 0, 0, 0);
                __builtin_amdgcn_s_setprio(0);
            }
        }
        // one barrier per iter: protects buf reuse AND makes prefetch visible
        __syncthreads();
    }

    // ---- partial epilogue: merge hi/lo half-sums, store unnormalized ----
    float lh = l_acc + __shfl_xor(l_acc, 32);
    float* po_h = half ? po1 : po0;
    int qrow = b * 2048 + qt * 128 + wave * 32 + l31;
#pragma unroll
    for (int db = 0; db < 2; db++) {
#pragma unroll
        for (int g = 0; g < 4; g++) {
            float4 stv;
            stv.x = oacc[db][g * 4 + 0];
            stv.y = oacc[db][g * 4 + 1];
            stv.z = oacc[db][g * 4 + 2];
            stv.w = oacc[db][g * 4 + 3];
            int col = h * 64 + db * 32 + g * 8 + hi * 4;
            *(float4*)&po_h[(size_t)qrow * 1024 + col] = stv;
        }
    }
    if (hi == 0)
        pl[((size_t)half * 4096 + qrow) * 16 + h] = lh;
}

// ---- merge: aout = bf16((po0 + po1) / (l0 + l1)), one block per row ----
__global__ __launch_bounds__(256) void merge_kernel(const float* __restrict__ po0,
                                                    const float* __restrict__ po1,
                                                    const float* __restrict__ pl,
                                                    U16* __restrict__ aout) {
    int row = blockIdx.x;
    int t = threadIdx.x;
    int h = t >> 4;                              // cols 4t..4t+3 all in head h
    float inv = 1.0f / (pl[(size_t)row * 16 + h] + pl[((size_t)4096 + row) * 16 + h]);
    float4 a = ((const float4*)(po0 + (size_t)row * 1024))[t];
    float4 c = ((const float4*)(po1 + (size_t)row * 1024))[t];
    ushort4 o;
    o.x = f2b((a.x + c.x) * inv);
    o.y = f2b((a.y + c.y) * inv);
    o.z = f2b((a.z + c.z) * inv);
    o.w = f2b((a.w + c.w) * inv);
    ((ushort4*)(aout + (size_t)row * 1024))[t] = o;
}

extern "C" void kernel_launch(void* const* d_in, const int* in_sizes, int n_in,
                              void* d_out, int out_size, void* d_ws, size_t ws_size,
                              hipStream_t stream) {
    (void)in_sizes; (void)n_in; (void)out_size; (void)ws_size;
    const float* x    = (const float*)d_in[0];
    const float* g    = (const float*)d_in[1];
    const float* be   = (const float*)d_in[2];
    const float* Wqkv = (const float*)d_in[3];
    const float* Wout = (const float*)d_in[4];
    const float* bout = (const float*)d_in[5];
    float* out = (float*)d_out;   // reference output dtype is fp32
    char* ws = (char*)d_ws;

    U16* xn   = (U16*)(ws);                          // 8 MB, reused as aout
    U16* qkv  = (U16*)(ws + (size_t)(8u  << 20));    // 24 MB (V third unused)
    U16* WqT  = (U16*)(ws + (size_t)(32u << 20));    // 6 MB
    U16* WoT  = (U16*)(ws + (size_t)(38u << 20));    // 2 MB
    U16* vT   = (U16*)(ws + (size_t)(40u << 20));    // 8 MB: V transposed
    float* po1 = (float*)(ws + (size_t)(48u << 20)); // 16 MB: split-K half-1 O
    float* pl  = (float*)(ws + (size_t)(64u << 20)); // 512 KB: row sums [2][4096][16]
    U16* aout = xn;  // xn dead after GEMM1; written by merge
    float* po0 = out;  // d_out as scratch: dead until GEMM2 overwrites it

    transpose_f2b<<<dim3(3072 / 32, 1024 / 32), dim3(32, 8), 0, stream>>>(Wqkv, WqT, 1024, 3072);
    transpose_f2b<<<dim3(1024 / 32, 1024 / 32), dim3(32, 8), 0, stream>>>(Wout, WoT, 1024, 1024);
    ln_kernel<<<4096, 256, 0, stream>>>(x, g, be, xn);
    gemm_bt<U16><<<dim3(3072 / 128, 4096 / 128), 256, 0, stream>>>(xn, WqT, nullptr, qkv, vT, 4096, 3072, 1024);
    attn_kernel<<<dim3(1024), 256, 0, stream>>>(qkv, vT, po0, po1, pl);
    merge_kernel<<<dim3(4096), 256, 0, stream>>>(po0, po1, pl, aout);
    gemm_bt<float><<<dim3(1024 / 128, 4096 / 128), 256, 0, stream>>>(aout, WoT, bout, out, nullptr, 4096, 1024, 1024);
}

// Round 5
// 197.989 us; speedup vs baseline: 1.0923x; 1.0923x over previous
//
#include <hip/hip_runtime.h>

typedef unsigned short U16;
typedef __bf16 bf16x8 __attribute__((ext_vector_type(8)));
typedef float f32x4 __attribute__((ext_vector_type(4)));
typedef float f32x16 __attribute__((ext_vector_type(16)));

__device__ inline float b2f(U16 u) {
    union { unsigned int i; float f; } v;
    v.i = ((unsigned int)u) << 16;
    return v.f;
}
__device__ inline U16 f2b(float f) {
    union { float f; unsigned int u; } v;
    v.f = f;
    unsigned int r = (v.u + 0x7fffu + ((v.u >> 16) & 1u)) >> 16;
    return (U16)r;
}

// pack two f32 -> two bf16 in one u32 (RNE, same as f2b)
__device__ inline unsigned cvt_pk(float lo, float hi) {
    unsigned d;
    asm("v_cvt_pk_bf16_f32 %0, %1, %2" : "=v"(d) : "v"(lo), "v"(hi));
    return d;
}
// swap: a[lanes 32-63] <-> b[lanes 0-31]
__device__ inline void plswap(unsigned &a, unsigned &b) {
    asm("v_permlane32_swap_b32 %0, %1" : "+v"(a), "+v"(b));
}

// async global->LDS, 16B per lane (LDS dest = wave-uniform base + lane*16)
__device__ inline void gld16(const void* g, void* l) {
    __builtin_amdgcn_global_load_lds(
        (const __attribute__((address_space(1))) void*)g,
        (__attribute__((address_space(3))) void*)l, 16, 0, 0);
}

// ------- Transpose + fp32->bf16, two tensors in one launch (blockIdx.z) ----
__global__ void transpose2_f2b(const float* __restrict__ inA, U16* __restrict__ outA,
                               int RA, int CA,
                               const float* __restrict__ inB, U16* __restrict__ outB,
                               int RB, int CB) {
    const float* in; U16* out; int R, C;
    if (blockIdx.z == 0) { in = inA; out = outA; R = RA; C = CA; }
    else {
        if ((int)blockIdx.x * 32 >= CB) return;   // uniform whole-block exit
        in = inB; out = outB; R = RB; C = CB;
    }
    __shared__ float tile[32][33];
    int c0 = blockIdx.x * 32, r0 = blockIdx.y * 32;
    int tx = threadIdx.x, ty = threadIdx.y; // 32 x 8
#pragma unroll
    for (int i = 0; i < 32; i += 8)
        tile[ty + i][tx] = in[(size_t)(r0 + ty + i) * C + c0 + tx];
    __syncthreads();
#pragma unroll
    for (int i = 0; i < 32; i += 8)
        out[(size_t)(c0 + ty + i) * R + r0 + tx] = f2b(tile[tx][ty + i]);
}

// ------- LayerNorm: fp32 in -> bf16 out, one block (256 thr) per 1024-row ---
__global__ __launch_bounds__(256) void ln_kernel(const float* __restrict__ x,
                                                 const float* __restrict__ gamma,
                                                 const float* __restrict__ beta,
                                                 U16* __restrict__ xn) {
    int row = blockIdx.x;
    int t = threadIdx.x;
    float4 raw = ((const float4*)(x + (size_t)row * 1024))[t];
    float v[4] = { raw.x, raw.y, raw.z, raw.w };
    float s = v[0] + v[1] + v[2] + v[3];
    float s2 = v[0] * v[0] + v[1] * v[1] + v[2] * v[2] + v[3] * v[3];
#pragma unroll
    for (int off = 32; off >= 1; off >>= 1) {
        s  += __shfl_xor(s,  off);
        s2 += __shfl_xor(s2, off);
    }
    __shared__ float red[8];
    if ((t & 63) == 0) { red[(t >> 6) * 2] = s; red[(t >> 6) * 2 + 1] = s2; }
    __syncthreads();
    float S  = red[0] + red[2] + red[4] + red[6];
    float S2 = red[1] + red[3] + red[5] + red[7];
    float mu = S * (1.0f / 1024.0f);
    float var = S2 * (1.0f / 1024.0f) - mu * mu;
    float rstd = rsqrtf(var + 1e-5f);
    float4 g4 = ((const float4*)gamma)[t];
    float4 b4 = ((const float4*)beta)[t];
    ushort4 o;
    o.x = f2b((v[0] - mu) * rstd * g4.x + b4.x);
    o.y = f2b((v[1] - mu) * rstd * g4.y + b4.y);
    o.z = f2b((v[2] - mu) * rstd * g4.z + b4.z);
    o.w = f2b((v[3] - mu) * rstd * g4.w + b4.w);
    ((ushort4*)(xn + (size_t)row * 1024))[t] = o;
}

// ------ GEMM: C[M,N] = A[M,K] * Bt[N,K]^T (+fp32 bias), OutT = U16 or float -
// m97 structure: 128x128 tile, BK=32, global_load_lds width=16 staging.
// If vT != nullptr: N-tiles with n0 >= 2048 (the V third of QKV) are written
// transposed to vT[(b*16+h)*64+d][token] instead of C.
template <typename OutT>
__global__ __launch_bounds__(256) void gemm_bt(const U16* __restrict__ A,
                                               const U16* __restrict__ Bt,
                                               const float* __restrict__ bias,
                                               OutT* __restrict__ C,
                                               U16* __restrict__ vT,
                                               int M, int N, int K) {
    __shared__ __align__(16) U16 As[128 * 32];
    __shared__ __align__(16) U16 Bs[128 * 32];
    const int m0 = blockIdx.y * 128, n0 = blockIdx.x * 128;
    const int t = threadIdx.x;
    const int wave = t >> 6, lane = t & 63, l15 = lane & 15, quad = lane >> 4;
    const int wm = (wave >> 1) * 64, wn = (wave & 1) * 64;

    f32x4 acc[4][4];
#pragma unroll
    for (int i = 0; i < 4; i++)
#pragma unroll
        for (int j = 0; j < 4; j++)
            acc[i][j] = (f32x4){0.f, 0.f, 0.f, 0.f};

    const int c0i = t, c1i = 256 + t;
    const int r0 = c0i >> 2, kq0 = c0i & 3;
    const int r1 = c1i >> 2, kq1 = c1i & 3;

    for (int k0 = 0; k0 < K; k0 += 32) {
        gld16(&A[(size_t)(m0 + r0) * K + k0 + kq0 * 8], &As[c0i * 8]);
        gld16(&Bt[(size_t)(n0 + r0) * K + k0 + kq0 * 8], &Bs[c0i * 8]);
        gld16(&A[(size_t)(m0 + r1) * K + k0 + kq1 * 8], &As[c1i * 8]);
        gld16(&Bt[(size_t)(n0 + r1) * K + k0 + kq1 * 8], &Bs[c1i * 8]);
        __syncthreads();
        bf16x8 af[4], bfr[4];
#pragma unroll
        for (int i = 0; i < 4; i++)
            af[i] = *(const bf16x8*)&As[(wm + i * 16 + l15) * 32 + quad * 8];
#pragma unroll
        for (int j = 0; j < 4; j++)
            bfr[j] = *(const bf16x8*)&Bs[(wn + j * 16 + l15) * 32 + quad * 8];
#pragma unroll
        for (int i = 0; i < 4; i++)
#pragma unroll
            for (int j = 0; j < 4; j++)
                acc[i][j] = __builtin_amdgcn_mfma_f32_16x16x32_bf16(
                    af[i], bfr[j], acc[i][j], 0, 0, 0);
        __syncthreads();
    }
    if (vT && n0 >= 2048) {
#pragma unroll
        for (int i = 0; i < 4; i++) {
#pragma unroll
            for (int j = 0; j < 4; j++) {
                int col = n0 + wn + j * 16 + l15 - 2048;
                int hh = col >> 6, dd = col & 63;
                int row0 = m0 + wm + i * 16 + quad * 4;
                int bb = row0 >> 11, nn = row0 & 2047;
                ushort4 st;
                st.x = f2b(acc[i][j][0]); st.y = f2b(acc[i][j][1]);
                st.z = f2b(acc[i][j][2]); st.w = f2b(acc[i][j][3]);
                *(ushort4*)&vT[((((size_t)bb * 16) + hh) * 64 + dd) * 2048 + nn] = st;
            }
        }
        return;
    }
#pragma unroll
    for (int i = 0; i < 4; i++) {
#pragma unroll
        for (int j = 0; j < 4; j++) {
            int col = n0 + wn + j * 16 + l15;
            float bv = bias ? bias[col] : 0.0f;
#pragma unroll
            for (int r = 0; r < 4; r++) {
                int row = m0 + wm + i * 16 + quad * 4 + r;
                float val = acc[i][j][r] + bv;
                if constexpr (sizeof(OutT) == 4)
                    C[(size_t)row * N + col] = val;
                else
                    C[(size_t)row * N + col] = f2b(val);
            }
        }
    }
}

// ------ GEMM2 variant: BM=64 x BN=128 tile -> 512 blocks (2/CU) for the
// M=4096,N=1024 out-projection. The 128x128 tile gave exactly 256 blocks =
// 1 block/CU = 1 wave/SIMD: zero inter-wave overlap, all barrier drains
// exposed. Same m97 staging/MFMA structure, wave-tile 32x64.
__global__ __launch_bounds__(256) void gemm_bt2(const U16* __restrict__ A,
                                                const U16* __restrict__ Bt,
                                                const float* __restrict__ bias,
                                                float* __restrict__ C,
                                                int M, int N, int K) {
    __shared__ __align__(16) U16 As[64 * 32];
    __shared__ __align__(16) U16 Bs[128 * 32];
    const int m0 = blockIdx.y * 64, n0 = blockIdx.x * 128;
    const int t = threadIdx.x;
    const int wave = t >> 6, lane = t & 63, l15 = lane & 15, quad = lane >> 4;
    const int wm = (wave >> 1) * 32, wn = (wave & 1) * 64;

    f32x4 acc[2][4];
#pragma unroll
    for (int i = 0; i < 2; i++)
#pragma unroll
        for (int j = 0; j < 4; j++)
            acc[i][j] = (f32x4){0.f, 0.f, 0.f, 0.f};

    const int rA = t >> 2, kqA = t & 3;   // A: 256 chunks; B: 512 chunks

    for (int k0 = 0; k0 < K; k0 += 32) {
        gld16(&A[(size_t)(m0 + rA) * K + k0 + kqA * 8], &As[t * 8]);
        gld16(&Bt[(size_t)(n0 + rA) * K + k0 + kqA * 8], &Bs[t * 8]);
        gld16(&Bt[(size_t)(n0 + 64 + rA) * K + k0 + kqA * 8], &Bs[(256 + t) * 8]);
        __syncthreads();
        bf16x8 af[2], bfr[4];
#pragma unroll
        for (int i = 0; i < 2; i++)
            af[i] = *(const bf16x8*)&As[(wm + i * 16 + l15) * 32 + quad * 8];
#pragma unroll
        for (int j = 0; j < 4; j++)
            bfr[j] = *(const bf16x8*)&Bs[(wn + j * 16 + l15) * 32 + quad * 8];
#pragma unroll
        for (int i = 0; i < 2; i++)
#pragma unroll
            for (int j = 0; j < 4; j++)
                acc[i][j] = __builtin_amdgcn_mfma_f32_16x16x32_bf16(
                    af[i], bfr[j], acc[i][j], 0, 0, 0);
        __syncthreads();
    }
#pragma unroll
    for (int i = 0; i < 2; i++) {
#pragma unroll
        for (int j = 0; j < 4; j++) {
            int col = n0 + wn + j * 16 + l15;
            float bv = bias[col];
#pragma unroll
            for (int r = 0; r < 4; r++) {
                int row = m0 + wm + i * 16 + quad * 4 + r;
                C[(size_t)row * N + col] = acc[i][j][r] + bv;
            }
        }
    }
}

// ---- MFMA flash attention, in-register softmax (r3 structure, VALU-trimmed).
//
// r4 post-mortem: split-K never raised measured occupancy past ~22% and its
// fixed costs (2x Q loads, 4x epilogue bytes, merge pass) lose net time ->
// reverted to the r3 single-pass structure (proven 60.5us). Counters still
// show VALUBusy ~50% >> MfmaUtil ~23%, so this round trims the VALU/issue
// path without touching the proven schedule:
//  * Q pre-scaled by 0.125*log2e ONCE at fragment load (kills the 32
//    per-iter v_mul on S^T; numerically equivalent, bf16-rounded either way).
//  * k-loop unrolled x2 with compile-time buffer pointers (kills the
//    per-address v_cndmask chains from Kt[kt&1] runtime selection).
//  * softmax row-sum in 4 parallel accumulators (breaks the 32-deep serial
//    fp32 add chain; combined at the end; reorder only).
//
// Structure (r3): swapped QK^T S^T = mfma(K,Q) 32x32x16 -> lane-local softmax
// sums; P->bf16 PV B-operand via v_cvt_pk_bf16_f32 + v_permlane32_swap_b32,
// all in registers; PV: O^T = mfma(V^T, P^T). XCD swizzle: all blocks of one
// (b,h) on one XCD (FETCH 71.7 -> 12 MB). LDS oct swizzle: chunk (row r,
// slot j) fetches global oct j^(r&7); readers take oct o of row r from slot
// o^(r&7). Coalescing unchanged, values bit-identical.
__global__ __launch_bounds__(256) void attn_kernel(const U16* __restrict__ qkv,
                                                   const U16* __restrict__ vT,
                                                   U16* __restrict__ attn_out) {
    const int p = blockIdx.x;                    // 0..511
    const int xcd = p & 7;
    const int slot = p >> 3;                     // 0..63 within XCD
    const int bh = ((slot & 3) << 3) | xcd;      // bh & 7 == XCD id
    const int qt = slot >> 2;                    // 0..15, 128 q-rows per block
    const int b = bh >> 4, h = bh & 15;
    const int t = threadIdx.x;
    const int wave = t >> 6, lane = t & 63;
    const int l31 = lane & 31, hi = lane >> 5;
    const float sc2 = 0.125f * 1.44269504089f;  // scale * log2(e)

    __shared__ __align__(16) U16 Kt[2][64 * 64];    // [key][d-swizzled]
    __shared__ __align__(16) U16 Vt[2][64 * 64];    // [d][key-swizzled]

    const size_t base = (size_t)(b * 2048) * 3072;
    const U16* vTbh = vT + ((size_t)(b * 16 + h) * 64) * 2048;

    // Q fragments (B-operand of swapped QK^T): lane(hi,q=l31) holds
    // Q[qrow][d = s*16 + hi*8 .. +8] for k-slices s=0..3.
    // Pre-scaled by sc2 so the softmax is exp2(S) with no per-iter mul.
    bf16x8 qf[4];
    {
        int qrow = qt * 128 + wave * 32 + l31;
        const U16* qp = qkv + base + (size_t)qrow * 3072 + h * 64 + hi * 8;
#pragma unroll
        for (int s = 0; s < 4; s++) {
            union { bf16x8 v; U16 u[8]; } a;
            a.v = *(const bf16x8*)&qp[s * 16];
#pragma unroll
            for (int e = 0; e < 8; e++) a.u[e] = f2b(b2f(a.u[e]) * sc2);
            qf[s] = a.v;
        }
    }

    float l4[4] = { 0.f, 0.f, 0.f, 0.f };
    f32x16 oacc[2];  // O^T[d][q]: d = db*32 + (reg&3)+8*(reg>>2)+4*hi, q=l31
#pragma unroll
    for (int db = 0; db < 2; db++)
#pragma unroll
        for (int r = 0; r < 16; r++)
            oacc[db][r] = 0.0f;

    // staging: chunk c -> LDS offset c*16B; row=c>>3, slot=c&7,
    // fetched global oct = slot ^ (row&7)
    const int c0 = t, c1 = 256 + t;
    const int row0 = c0 >> 3, oct0 = (c0 & 7) ^ (row0 & 7);
    const int row1 = c1 >> 3, oct1 = (c1 & 7) ^ (row1 & 7);

    // prefetch tile 0 into buf 0
    gld16(&qkv[base + (size_t)row0 * 3072 + 1024 + h * 64 + oct0 * 8], &Kt[0][c0 * 8]);
    gld16(&qkv[base + (size_t)row1 * 3072 + 1024 + h * 64 + oct1 * 8], &Kt[0][c1 * 8]);
    gld16(&vTbh[(size_t)row0 * 2048 + oct0 * 8], &Vt[0][c0 * 8]);
    gld16(&vTbh[(size_t)row1 * 2048 + oct1 * 8], &Vt[0][c1 * 8]);
    __syncthreads();

    // one k-tile step; KtC/VtC = current buf (compile-time at call sites),
    // KtN/VtN = next buf, nt = tile to prefetch (wraps harmlessly at end)
    auto step = [&](const U16* KtC, const U16* VtC, U16* KtN, U16* VtN, int nt) {
        gld16(&qkv[base + (size_t)(nt * 64 + row0) * 3072 + 1024 + h * 64 + oct0 * 8], &KtN[c0 * 8]);
        gld16(&qkv[base + (size_t)(nt * 64 + row1) * 3072 + 1024 + h * 64 + oct1 * 8], &KtN[c1 * 8]);
        gld16(&vTbh[(size_t)row0 * 2048 + nt * 64 + oct0 * 8], &VtN[c0 * 8]);
        gld16(&vTbh[(size_t)row1 * 2048 + nt * 64 + oct1 * 8], &VtN[c1 * 8]);
#pragma unroll
        for (int kb = 0; kb < 2; kb++) {
            // K A-frags: K[key = kb*32+l31][d = s*16 + hi*8 ..+8]
            bf16x8 kf[4];
#pragma unroll
            for (int s = 0; s < 4; s++)
                kf[s] = *(const bf16x8*)&KtC[(kb * 32 + l31) * 64 +
                                             (((s * 2 + hi) ^ (l31 & 7)) * 8)];
            // V A-frags issued early (latency under QK^T + softmax):
            // V^T[d = db*32+l31][key = kb*32 + s*16 + hi*8 ..+8]
            bf16x8 vfr[2][2];
#pragma unroll
            for (int db = 0; db < 2; db++)
#pragma unroll
                for (int s = 0; s < 2; s++)
                    vfr[db][s] = *(const bf16x8*)&VtC[(db * 32 + l31) * 64 +
                                                      (((kb * 4 + s * 2 + hi) ^ (l31 & 7)) * 8)];

            // QK^T: S^T[key][q] (Q pre-scaled)
            f32x16 st = {0.f, 0.f, 0.f, 0.f, 0.f, 0.f, 0.f, 0.f,
                         0.f, 0.f, 0.f, 0.f, 0.f, 0.f, 0.f, 0.f};
            __builtin_amdgcn_s_setprio(1);
#pragma unroll
            for (int s = 0; s < 4; s++)
                st = __builtin_amdgcn_mfma_f32_32x32x16_bf16(kf[s], qf[s], st, 0, 0, 0);
            __builtin_amdgcn_s_setprio(0);

            // softmax (static, exp2), 4 parallel lane-local sums
            float pe[16];
#pragma unroll
            for (int r = 0; r < 16; r++) {
                pe[r] = __builtin_amdgcn_exp2f(st[r]);
                l4[r & 3] += pe[r];
            }

            // pack P^T into PV B-frags (registers only):
            // regs s*8 + {0..7} = keys kb*32 + s*16 + {4hi+0..3, 8+4hi+0..3};
            // after 2 swaps per slice, word e holds keys (hi*8+2e, hi*8+2e+1).
#pragma unroll
            for (int s = 0; s < 2; s++) {
                unsigned p01 = cvt_pk(pe[s * 8 + 0], pe[s * 8 + 1]);
                unsigned p23 = cvt_pk(pe[s * 8 + 2], pe[s * 8 + 3]);
                unsigned p45 = cvt_pk(pe[s * 8 + 4], pe[s * 8 + 5]);
                unsigned p67 = cvt_pk(pe[s * 8 + 6], pe[s * 8 + 7]);
                plswap(p01, p45);
                plswap(p23, p67);
                union { unsigned u[4]; bf16x8 v; } pw;
                pw.u[0] = p01; pw.u[1] = p23; pw.u[2] = p45; pw.u[3] = p67;
                // PV: O^T += V^T x P^T
                __builtin_amdgcn_s_setprio(1);
#pragma unroll
                for (int db = 0; db < 2; db++)
                    oacc[db] = __builtin_amdgcn_mfma_f32_32x32x16_bf16(
                        vfr[db][s], pw.v, oacc[db], 0, 0, 0);
                __builtin_amdgcn_s_setprio(0);
            }
        }
        // one barrier per step: protects buf reuse AND makes prefetch visible
        __syncthreads();
    };

    for (int kt2 = 0; kt2 < 16; kt2++) {
        step(&Kt[0][0], &Vt[0][0], &Kt[1][0], &Vt[1][0], 2 * kt2 + 1);
        step(&Kt[1][0], &Vt[1][0], &Kt[0][0], &Vt[0][0], (2 * kt2 + 2) & 31);
    }

    // ---- epilogue: combine sums, merge hi/lo halves, normalize, store ----
    float l_acc = (l4[0] + l4[1]) + (l4[2] + l4[3]);
    float lt = l_acc + __shfl_xor(l_acc, 32);
    float inv = 1.0f / lt;
    int qrow = b * 2048 + qt * 128 + wave * 32 + l31;
#pragma unroll
    for (int db = 0; db < 2; db++) {
#pragma unroll
        for (int g = 0; g < 4; g++) {
            ushort4 stv;
            stv.x = f2b(oacc[db][g * 4 + 0] * inv);
            stv.y = f2b(oacc[db][g * 4 + 1] * inv);
            stv.z = f2b(oacc[db][g * 4 + 2] * inv);
            stv.w = f2b(oacc[db][g * 4 + 3] * inv);
            int col = h * 64 + db * 32 + g * 8 + hi * 4;
            *(ushort4*)&attn_out[(size_t)qrow * 1024 + col] = stv;
        }
    }
}

extern "C" void kernel_launch(void* const* d_in, const int* in_sizes, int n_in,
                              void* d_out, int out_size, void* d_ws, size_t ws_size,
                              hipStream_t stream) {
    (void)in_sizes; (void)n_in; (void)out_size; (void)ws_size;
    const float* x    = (const float*)d_in[0];
    const float* g    = (const float*)d_in[1];
    const float* be   = (const float*)d_in[2];
    const float* Wqkv = (const float*)d_in[3];
    const float* Wout = (const float*)d_in[4];
    const float* bout = (const float*)d_in[5];
    float* out = (float*)d_out;   // reference output dtype is fp32
    char* ws = (char*)d_ws;

    U16* xn   = (U16*)(ws);                          // 8 MB, reused as aout
    U16* qkv  = (U16*)(ws + (size_t)(8u  << 20));    // 24 MB (V third unused)
    U16* WqT  = (U16*)(ws + (size_t)(32u << 20));    // 6 MB
    U16* WoT  = (U16*)(ws + (size_t)(38u << 20));    // 2 MB
    U16* vT   = (U16*)(ws + (size_t)(40u << 20));    // 8 MB: V transposed
    U16* aout = xn;  // xn dead after GEMM1

    transpose2_f2b<<<dim3(3072 / 32, 1024 / 32, 2), dim3(32, 8), 0, stream>>>(
        Wqkv, WqT, 1024, 3072, Wout, WoT, 1024, 1024);
    ln_kernel<<<4096, 256, 0, stream>>>(x, g, be, xn);
    gemm_bt<U16><<<dim3(3072 / 128, 4096 / 128), 256, 0, stream>>>(xn, WqT, nullptr, qkv, vT, 4096, 3072, 1024);
    attn_kernel<<<dim3(512), 256, 0, stream>>>(qkv, vT, aout);
    gemm_bt2<<<dim3(1024 / 128, 4096 / 64), 256, 0, stream>>>(aout, WoT, bout, out, 4096, 1024, 1024);
}

// Round 7
// 193.447 us; speedup vs baseline: 1.1180x; 1.0235x over previous
//
#include <hip/hip_runtime.h>

typedef unsigned short U16;
typedef __bf16 bf16x8 __attribute__((ext_vector_type(8)));
typedef float f32x4 __attribute__((ext_vector_type(4)));
typedef float f32x16 __attribute__((ext_vector_type(16)));

__device__ inline float b2f(U16 u) {
    union { unsigned int i; float f; } v;
    v.i = ((unsigned int)u) << 16;
    return v.f;
}
__device__ inline U16 f2b(float f) {
    union { float f; unsigned int u; } v;
    v.f = f;
    unsigned int r = (v.u + 0x7fffu + ((v.u >> 16) & 1u)) >> 16;
    return (U16)r;
}

// pack two f32 -> two bf16 in one u32 (RNE, same as f2b)
__device__ inline unsigned cvt_pk(float lo, float hi) {
    unsigned d;
    asm("v_cvt_pk_bf16_f32 %0, %1, %2" : "=v"(d) : "v"(lo), "v"(hi));
    return d;
}
// swap: a[lanes 32-63] <-> b[lanes 0-31]
__device__ inline void plswap(unsigned &a, unsigned &b) {
    asm("v_permlane32_swap_b32 %0, %1" : "+v"(a), "+v"(b));
}

// async global->LDS, 16B per lane (LDS dest = wave-uniform base + lane*16)
__device__ inline void gld16(const void* g, void* l) {
    __builtin_amdgcn_global_load_lds(
        (const __attribute__((address_space(1))) void*)g,
        (__attribute__((address_space(3))) void*)l, 16, 0, 0);
}

// ------- prep: LN (blocks 0..4095) + two weight transposes, ONE launch -----
__global__ __launch_bounds__(256) void prep_kernel(const float* __restrict__ x,
                                                   const float* __restrict__ gamma,
                                                   const float* __restrict__ beta,
                                                   U16* __restrict__ xn,
                                                   const float* __restrict__ Wqkv,
                                                   U16* __restrict__ WqT,
                                                   const float* __restrict__ Wout,
                                                   U16* __restrict__ WoT) {
    int p = blockIdx.x;
    int t = threadIdx.x;
    if (p < 4096) {
        // ---- LayerNorm row p: fp32 -> bf16 ----
        int row = p;
        float4 raw = ((const float4*)(x + (size_t)row * 1024))[t];
        float v[4] = { raw.x, raw.y, raw.z, raw.w };
        float s = v[0] + v[1] + v[2] + v[3];
        float s2 = v[0] * v[0] + v[1] * v[1] + v[2] * v[2] + v[3] * v[3];
#pragma unroll
        for (int off = 32; off >= 1; off >>= 1) {
            s  += __shfl_xor(s,  off);
            s2 += __shfl_xor(s2, off);
        }
        __shared__ float red[8];
        if ((t & 63) == 0) { red[(t >> 6) * 2] = s; red[(t >> 6) * 2 + 1] = s2; }
        __syncthreads();
        float S  = red[0] + red[2] + red[4] + red[6];
        float S2 = red[1] + red[3] + red[5] + red[7];
        float mu = S * (1.0f / 1024.0f);
        float var = S2 * (1.0f / 1024.0f) - mu * mu;
        float rstd = rsqrtf(var + 1e-5f);
        float4 g4 = ((const float4*)gamma)[t];
        float4 b4 = ((const float4*)beta)[t];
        ushort4 o;
        o.x = f2b((v[0] - mu) * rstd * g4.x + b4.x);
        o.y = f2b((v[1] - mu) * rstd * g4.y + b4.y);
        o.z = f2b((v[2] - mu) * rstd * g4.z + b4.z);
        o.w = f2b((v[3] - mu) * rstd * g4.w + b4.w);
        ((ushort4*)(xn + (size_t)row * 1024))[t] = o;
        return;
    }
    // ---- transpose + f2b: out[c][r] = bf16(in[r][c]) ----
    p -= 4096;
    const float* in; U16* out; int C, tilesx;
    if (p < 3072) { in = Wqkv; out = WqT; C = 3072; tilesx = 96; }
    else { p -= 3072; in = Wout; out = WoT; C = 1024; tilesx = 32; }
    const int R = 1024;
    int c0 = (p % tilesx) * 32, r0 = (p / tilesx) * 32;
    int tx = t & 31, ty = t >> 5;   // 32 x 8
    __shared__ float tile[32][33];
#pragma unroll
    for (int i = 0; i < 32; i += 8)
        tile[ty + i][tx] = in[(size_t)(r0 + ty + i) * C + c0 + tx];
    __syncthreads();
#pragma unroll
    for (int i = 0; i < 32; i += 8)
        out[(size_t)(c0 + ty + i) * R + r0 + tx] = f2b(tile[tx][ty + i]);
}

// ------ GEMM1: 256x256 tile, BK=64, 8 waves, counted-vmcnt pipeline (T3+T4).
// C[M,3072] = A[M,K] * Bt[N,K]^T, U16 out; n0 >= 2048 (V third) goes
// transposed to vT[(b*16+h)*64+d][token].
//
// Re-submit of r5's design (container failed twice with no kernel signal;
// hang-path audit found none: uniform barriers, vmcnt ledger retires exactly
// one tile, LDS chunk writes end exactly at the 16 KB half-tile boundary).
// Hardening: dropped the ",2" from launch_bounds — it capped VGPRs at 256
// with ~200+ live, risking scratch spills, and bought nothing (128 KB LDS
// already limits to 1 block/CU).
//
// Schedule per K-tile t (vmcnt ledger, per wave, 4 loads per stA/stB):
//   issue A(t+1); s_waitcnt vmcnt(4)   <- retires A(t)+B(t) exactly,
//   s_barrier                             A(t+1) stays IN FLIGHT
//   P0: ds_read B(all) + A(0..3); issue B(t+1); 32 MFMA   [setprio 1]
//   s_barrier
//   P1: ds_read A(4..7); 32 MFMA                           [setprio 1]
//   s_barrier   (protects buf reuse)
// NEVER vmcnt(0) in the loop (T4). Oct swizzle as attn (proven r0-r5):
// chunk c -> row c>>3, slot c&7, fetches global oct (c&7)^(row&7); reader
// takes oct o of row r from slot o^(r&7); frag reads are 2-way = free (m136).
// XCD-chunked decode: 192 blocks, XCD p&7 owns grid-rows {2*xcd, 2*xcd+1}.
__global__ __launch_bounds__(512) void gemm256(const U16* __restrict__ A,
                                               const U16* __restrict__ Bt,
                                               U16* __restrict__ C,
                                               U16* __restrict__ vT,
                                               int M, int N, int K) {
    __shared__ __align__(16) U16 As[2][2][128 * 64];
    __shared__ __align__(16) U16 Bs[2][2][128 * 64];
    const int p = blockIdx.x;
    const int xcd = p & 7, sl = p >> 3;              // sl in 0..23
    const int by = xcd * 2 + (sl >= 12 ? 1 : 0);
    const int bx = (sl >= 12) ? (sl - 12) : sl;
    const int m0 = by * 256, n0 = bx * 256;
    const int t = threadIdx.x;
    const int wave = t >> 6, lane = t & 63, l15 = lane & 15, quad = lane >> 4;
    const int wm = wave >> 2, wn = wave & 3;

    f32x4 acc[8][4];
#pragma unroll
    for (int i = 0; i < 8; i++)
#pragma unroll
        for (int j = 0; j < 4; j++)
            acc[i][j] = (f32x4){0.f, 0.f, 0.f, 0.f};

    // staging coords: chunks c0 = t, c1 = 512 + t (1024 chunks per half-tile)
    const int c0 = t, c1 = 512 + t;
    const int sr0 = c0 >> 3, so0 = (c0 & 7) ^ (sr0 & 7);
    const int sr1 = c1 >> 3, so1 = (c1 & 7) ^ (sr1 & 7);
    const U16* Ag0 = A + (size_t)(m0 + sr0) * K + so0 * 8;
    const U16* Ag1 = A + (size_t)(m0 + sr1) * K + so1 * 8;
    const U16* Bg0 = Bt + (size_t)(n0 + sr0) * K + so0 * 8;
    const U16* Bg1 = Bt + (size_t)(n0 + sr1) * K + so1 * 8;
    const size_t hstep = (size_t)128 * K;           // +128 rows

    auto stA = [&](int kt, U16* d0, U16* d1) {      // 4 loads
        gld16(Ag0 + kt * 64, d0 + c0 * 8);
        gld16(Ag1 + kt * 64, d0 + c1 * 8);
        gld16(Ag0 + hstep + kt * 64, d1 + c0 * 8);
        gld16(Ag1 + hstep + kt * 64, d1 + c1 * 8);
    };
    auto stB = [&](int kt, U16* d0, U16* d1) {      // 4 loads
        gld16(Bg0 + kt * 64, d0 + c0 * 8);
        gld16(Bg1 + kt * 64, d0 + c1 * 8);
        gld16(Bg0 + hstep + kt * 64, d1 + c0 * 8);
        gld16(Bg1 + hstep + kt * 64, d1 + c1 * 8);
    };

    // frag-read offsets (elements): row l15 within 16-row frag, oct = quad
    // (k 0..31) or 4+quad (k 32..63); row-group strides are all == 0 mod 8.
    const int slot0 = quad ^ (l15 & 7);
    const int slot1 = (4 + quad) ^ (l15 & 7);
    const int aoff0 = l15 * 64 + slot0 * 8, aoff1 = l15 * 64 + slot1 * 8;
    const int bbase = (wn & 1) * 64 * 64;           // n-sub-half within 128-half
    const int boff0 = bbase + aoff0, boff1 = bbase + aoff1;
    const int nk = K >> 6;

    auto ktile = [&](const U16* Ac0, const U16* Ac1, const U16* Bc0, const U16* Bc1,
                     U16* An0, U16* An1, U16* Bn0, U16* Bn1, int kt) {
        const bool nx = (kt + 1) < nk;
        if (nx) {
            stA(kt + 1, An0, An1);
            asm volatile("s_waitcnt vmcnt(4)" ::: "memory");
        } else {
            asm volatile("s_waitcnt vmcnt(0)" ::: "memory");
        }
        __builtin_amdgcn_s_barrier();
        asm volatile("" ::: "memory");
        const U16* Ah = wm ? Ac1 : Ac0;
        const U16* Bh = (wn & 2) ? Bc1 : Bc0;
        bf16x8 bfr[4][2], af[4][2];
#pragma unroll
        for (int j = 0; j < 4; j++) {
            bfr[j][0] = *(const bf16x8*)&Bh[j * 16 * 64 + boff0];
            bfr[j][1] = *(const bf16x8*)&Bh[j * 16 * 64 + boff1];
        }
#pragma unroll
        for (int i = 0; i < 4; i++) {
            af[i][0] = *(const bf16x8*)&Ah[i * 16 * 64 + aoff0];
            af[i][1] = *(const bf16x8*)&Ah[i * 16 * 64 + aoff1];
        }
        if (nx) stB(kt + 1, Bn0, Bn1);
        __builtin_amdgcn_s_setprio(1);
#pragma unroll
        for (int i = 0; i < 4; i++)
#pragma unroll
            for (int j = 0; j < 4; j++) {
                acc[i][j] = __builtin_amdgcn_mfma_f32_16x16x32_bf16(af[i][0], bfr[j][0], acc[i][j], 0, 0, 0);
                acc[i][j] = __builtin_amdgcn_mfma_f32_16x16x32_bf16(af[i][1], bfr[j][1], acc[i][j], 0, 0, 0);
            }
        __builtin_amdgcn_s_setprio(0);
        asm volatile("" ::: "memory");
        __builtin_amdgcn_s_barrier();
        asm volatile("" ::: "memory");
#pragma unroll
        for (int i = 0; i < 4; i++) {
            af[i][0] = *(const bf16x8*)&Ah[(4 + i) * 16 * 64 + aoff0];
            af[i][1] = *(const bf16x8*)&Ah[(4 + i) * 16 * 64 + aoff1];
        }
        __builtin_amdgcn_s_setprio(1);
#pragma unroll
        for (int i = 0; i < 4; i++)
#pragma unroll
            for (int j = 0; j < 4; j++) {
                acc[4 + i][j] = __builtin_amdgcn_mfma_f32_16x16x32_bf16(af[i][0], bfr[j][0], acc[4 + i][j], 0, 0, 0);
                acc[4 + i][j] = __builtin_amdgcn_mfma_f32_16x16x32_bf16(af[i][1], bfr[j][1], acc[4 + i][j], 0, 0, 0);
            }
        __builtin_amdgcn_s_setprio(0);
        asm volatile("" ::: "memory");
        __builtin_amdgcn_s_barrier();
        asm volatile("" ::: "memory");
    };

    // prologue: tile 0 -> buf 0, full drain once
    stA(0, &As[0][0][0], &As[0][1][0]);
    stB(0, &Bs[0][0][0], &Bs[0][1][0]);
    asm volatile("s_waitcnt vmcnt(0)" ::: "memory");
    __builtin_amdgcn_s_barrier();
    asm volatile("" ::: "memory");

    for (int kt = 0; kt < nk; kt += 2) {
        ktile(&As[0][0][0], &As[0][1][0], &Bs[0][0][0], &Bs[0][1][0],
              &As[1][0][0], &As[1][1][0], &Bs[1][0][0], &Bs[1][1][0], kt);
        ktile(&As[1][0][0], &As[1][1][0], &Bs[1][0][0], &Bs[1][1][0],
              &As[0][0][0], &As[0][1][0], &Bs[0][0][0], &Bs[0][1][0], kt + 1);
    }

    if (vT && n0 >= 2048) {
#pragma unroll
        for (int i = 0; i < 8; i++) {
#pragma unroll
            for (int j = 0; j < 4; j++) {
                int col = n0 + wn * 64 + j * 16 + l15 - 2048;
                int hh = col >> 6, dd = col & 63;
                int row0 = m0 + wm * 128 + i * 16 + quad * 4;
                int bb = row0 >> 11, nn = row0 & 2047;
                ushort4 st;
                st.x = f2b(acc[i][j][0]); st.y = f2b(acc[i][j][1]);
                st.z = f2b(acc[i][j][2]); st.w = f2b(acc[i][j][3]);
                *(ushort4*)&vT[((((size_t)bb * 16) + hh) * 64 + dd) * 2048 + nn] = st;
            }
        }
        return;
    }
#pragma unroll
    for (int i = 0; i < 8; i++) {
#pragma unroll
        for (int j = 0; j < 4; j++) {
            int col = n0 + wn * 64 + j * 16 + l15;
#pragma unroll
            for (int r = 0; r < 4; r++) {
                int row = m0 + wm * 128 + i * 16 + quad * 4 + r;
                C[(size_t)row * N + col] = f2b(acc[i][j][r]);
            }
        }
    }
}

// ------ GEMM2: BM=64 x BN=128 tile -> 512 blocks (2/CU) for the out-proj.
__global__ __launch_bounds__(256) void gemm_bt2(const U16* __restrict__ A,
                                                const U16* __restrict__ Bt,
                                                const float* __restrict__ bias,
                                                float* __restrict__ C,
                                                int M, int N, int K) {
    __shared__ __align__(16) U16 As[64 * 32];
    __shared__ __align__(16) U16 Bs[128 * 32];
    const int m0 = blockIdx.y * 64, n0 = blockIdx.x * 128;
    const int t = threadIdx.x;
    const int wave = t >> 6, lane = t & 63, l15 = lane & 15, quad = lane >> 4;
    const int wm = (wave >> 1) * 32, wn = (wave & 1) * 64;

    f32x4 acc[2][4];
#pragma unroll
    for (int i = 0; i < 2; i++)
#pragma unroll
        for (int j = 0; j < 4; j++)
            acc[i][j] = (f32x4){0.f, 0.f, 0.f, 0.f};

    const int rA = t >> 2, kqA = t & 3;

    for (int k0 = 0; k0 < K; k0 += 32) {
        gld16(&A[(size_t)(m0 + rA) * K + k0 + kqA * 8], &As[t * 8]);
        gld16(&Bt[(size_t)(n0 + rA) * K + k0 + kqA * 8], &Bs[t * 8]);
        gld16(&Bt[(size_t)(n0 + 64 + rA) * K + k0 + kqA * 8], &Bs[(256 + t) * 8]);
        __syncthreads();
        bf16x8 af[2], bfr[4];
#pragma unroll
        for (int i = 0; i < 2; i++)
            af[i] = *(const bf16x8*)&As[(wm + i * 16 + l15) * 32 + quad * 8];
#pragma unroll
        for (int j = 0; j < 4; j++)
            bfr[j] = *(const bf16x8*)&Bs[(wn + j * 16 + l15) * 32 + quad * 8];
#pragma unroll
        for (int i = 0; i < 2; i++)
#pragma unroll
            for (int j = 0; j < 4; j++)
                acc[i][j] = __builtin_amdgcn_mfma_f32_16x16x32_bf16(
                    af[i], bfr[j], acc[i][j], 0, 0, 0);
        __syncthreads();
    }
#pragma unroll
    for (int i = 0; i < 2; i++) {
#pragma unroll
        for (int j = 0; j < 4; j++) {
            int col = n0 + wn + j * 16 + l15;
            float bv = bias[col];
#pragma unroll
            for (int r = 0; r < 4; r++) {
                int row = m0 + wm + i * 16 + quad * 4 + r;
                C[(size_t)row * N + col] = acc[i][j][r] + bv;
            }
        }
    }
}

// ---- MFMA flash attention, in-register softmax (r5, proven 54.9us) --------
__global__ __launch_bounds__(256) void attn_kernel(const U16* __restrict__ qkv,
                                                   const U16* __restrict__ vT,
                                                   U16* __restrict__ attn_out) {
    const int p = blockIdx.x;                    // 0..511
    const int xcd = p & 7;
    const int slot = p >> 3;                     // 0..63 within XCD
    const int bh = ((slot & 3) << 3) | xcd;      // bh & 7 == XCD id
    const int qt = slot >> 2;                    // 0..15, 128 q-rows per block
    const int b = bh >> 4, h = bh & 15;
    const int t = threadIdx.x;
    const int wave = t >> 6, lane = t & 63;
    const int l31 = lane & 31, hi = lane >> 5;
    const float sc2 = 0.125f * 1.44269504089f;  // scale * log2(e)

    __shared__ __align__(16) U16 Kt[2][64 * 64];    // [key][d-swizzled]
    __shared__ __align__(16) U16 Vt[2][64 * 64];    // [d][key-swizzled]

    const size_t base = (size_t)(b * 2048) * 3072;
    const U16* vTbh = vT + ((size_t)(b * 16 + h) * 64) * 2048;

    // Q fragments, pre-scaled by sc2 (softmax = exp2(S) with no per-iter mul)
    bf16x8 qf[4];
    {
        int qrow = qt * 128 + wave * 32 + l31;
        const U16* qp = qkv + base + (size_t)qrow * 3072 + h * 64 + hi * 8;
#pragma unroll
        for (int s = 0; s < 4; s++) {
            union { bf16x8 v; U16 u[8]; } a;
            a.v = *(const bf16x8*)&qp[s * 16];
#pragma unroll
            for (int e = 0; e < 8; e++) a.u[e] = f2b(b2f(a.u[e]) * sc2);
            qf[s] = a.v;
        }
    }

    float l4[4] = { 0.f, 0.f, 0.f, 0.f };
    f32x16 oacc[2];  // O^T[d][q]: d = db*32 + (reg&3)+8*(reg>>2)+4*hi, q=l31
#pragma unroll
    for (int db = 0; db < 2; db++)
#pragma unroll
        for (int r = 0; r < 16; r++)
            oacc[db][r] = 0.0f;

    // staging: chunk c -> LDS offset c*16B; row=c>>3, slot=c&7,
    // fetched global oct = slot ^ (row&7)
    const int c0 = t, c1 = 256 + t;
    const int row0 = c0 >> 3, oct0 = (c0 & 7) ^ (row0 & 7);
    const int row1 = c1 >> 3, oct1 = (c1 & 7) ^ (row1 & 7);

    // prefetch tile 0 into buf 0
    gld16(&qkv[base + (size_t)row0 * 3072 + 1024 + h * 64 + oct0 * 8], &Kt[0][c0 * 8]);
    gld16(&qkv[base + (size_t)row1 * 3072 + 1024 + h * 64 + oct1 * 8], &Kt[0][c1 * 8]);
    gld16(&vTbh[(size_t)row0 * 2048 + oct0 * 8], &Vt[0][c0 * 8]);
    gld16(&vTbh[(size_t)row1 * 2048 + oct1 * 8], &Vt[0][c1 * 8]);
    __syncthreads();

    auto step = [&](const U16* KtC, const U16* VtC, U16* KtN, U16* VtN, int nt) {
        gld16(&qkv[base + (size_t)(nt * 64 + row0) * 3072 + 1024 + h * 64 + oct0 * 8], &KtN[c0 * 8]);
        gld16(&qkv[base + (size_t)(nt * 64 + row1) * 3072 + 1024 + h * 64 + oct1 * 8], &KtN[c1 * 8]);
        gld16(&vTbh[(size_t)row0 * 2048 + nt * 64 + oct0 * 8], &VtN[c0 * 8]);
        gld16(&vTbh[(size_t)row1 * 2048 + nt * 64 + oct1 * 8], &VtN[c1 * 8]);
#pragma unroll
        for (int kb = 0; kb < 2; kb++) {
            bf16x8 kf[4];
#pragma unroll
            for (int s = 0; s < 4; s++)
                kf[s] = *(const bf16x8*)&KtC[(kb * 32 + l31) * 64 +
                                             (((s * 2 + hi) ^ (l31 & 7)) * 8)];
            bf16x8 vfr[2][2];
#pragma unroll
            for (int db = 0; db < 2; db++)
#pragma unroll
                for (int s = 0; s < 2; s++)
                    vfr[db][s] = *(const bf16x8*)&VtC[(db * 32 + l31) * 64 +
                                                      (((kb * 4 + s * 2 + hi) ^ (l31 & 7)) * 8)];

            f32x16 st = {0.f, 0.f, 0.f, 0.f, 0.f, 0.f, 0.f, 0.f,
                         0.f, 0.f, 0.f, 0.f, 0.f, 0.f, 0.f, 0.f};
            __builtin_amdgcn_s_setprio(1);
#pragma unroll
            for (int s = 0; s < 4; s++)
                st = __builtin_amdgcn_mfma_f32_32x32x16_bf16(kf[s], qf[s], st, 0, 0, 0);
            __builtin_amdgcn_s_setprio(0);

            float pe[16];
#pragma unroll
            for (int r = 0; r < 16; r++) {
                pe[r] = __builtin_amdgcn_exp2f(st[r]);
                l4[r & 3] += pe[r];
            }

#pragma unroll
            for (int s = 0; s < 2; s++) {
                unsigned p01 = cvt_pk(pe[s * 8 + 0], pe[s * 8 + 1]);
                unsigned p23 = cvt_pk(pe[s * 8 + 2], pe[s * 8 + 3]);
                unsigned p45 = cvt_pk(pe[s * 8 + 4], pe[s * 8 + 5]);
                unsigned p67 = cvt_pk(pe[s * 8 + 6], pe[s * 8 + 7]);
                plswap(p01, p45);
                plswap(p23, p67);
                union { unsigned u[4]; bf16x8 v; } pw;
                pw.u[0] = p01; pw.u[1] = p23; pw.u[2] = p45; pw.u[3] = p67;
                __builtin_amdgcn_s_setprio(1);
#pragma unroll
                for (int db = 0; db < 2; db++)
                    oacc[db] = __builtin_amdgcn_mfma_f32_32x32x16_bf16(
                        vfr[db][s], pw.v, oacc[db], 0, 0, 0);
                __builtin_amdgcn_s_setprio(0);
            }
        }
        __syncthreads();
    };

    for (int kt2 = 0; kt2 < 16; kt2++) {
        step(&Kt[0][0], &Vt[0][0], &Kt[1][0], &Vt[1][0], 2 * kt2 + 1);
        step(&Kt[1][0], &Vt[1][0], &Kt[0][0], &Vt[0][0], (2 * kt2 + 2) & 31);
    }

    float l_acc = (l4[0] + l4[1]) + (l4[2] + l4[3]);
    float lt = l_acc + __shfl_xor(l_acc, 32);
    float inv = 1.0f / lt;
    int qrow = b * 2048 + qt * 128 + wave * 32 + l31;
#pragma unroll
    for (int db = 0; db < 2; db++) {
#pragma unroll
        for (int g = 0; g < 4; g++) {
            ushort4 stv;
            stv.x = f2b(oacc[db][g * 4 + 0] * inv);
            stv.y = f2b(oacc[db][g * 4 + 1] * inv);
            stv.z = f2b(oacc[db][g * 4 + 2] * inv);
            stv.w = f2b(oacc[db][g * 4 + 3] * inv);
            int col = h * 64 + db * 32 + g * 8 + hi * 4;
            *(ushort4*)&attn_out[(size_t)qrow * 1024 + col] = stv;
        }
    }
}

extern "C" void kernel_launch(void* const* d_in, const int* in_sizes, int n_in,
                              void* d_out, int out_size, void* d_ws, size_t ws_size,
                              hipStream_t stream) {
    (void)in_sizes; (void)n_in; (void)out_size; (void)ws_size;
    const float* x    = (const float*)d_in[0];
    const float* g    = (const float*)d_in[1];
    const float* be   = (const float*)d_in[2];
    const float* Wqkv = (const float*)d_in[3];
    const float* Wout = (const float*)d_in[4];
    const float* bout = (const float*)d_in[5];
    float* out = (float*)d_out;   // reference output dtype is fp32
    char* ws = (char*)d_ws;

    U16* xn   = (U16*)(ws);                          // 8 MB, reused as aout
    U16* qkv  = (U16*)(ws + (size_t)(8u  << 20));    // 24 MB (V third unused)
    U16* WqT  = (U16*)(ws + (size_t)(32u << 20));    // 6 MB
    U16* WoT  = (U16*)(ws + (size_t)(38u << 20));    // 2 MB
    U16* vT   = (U16*)(ws + (size_t)(40u << 20));    // 8 MB: V transposed
    U16* aout = xn;  // xn dead after GEMM1

    prep_kernel<<<8192, 256, 0, stream>>>(x, g, be, xn, Wqkv, WqT, Wout, WoT);
    gemm256<<<192, 512, 0, stream>>>(xn, WqT, qkv, vT, 4096, 3072, 1024);
    attn_kernel<<<512, 256, 0, stream>>>(qkv, vT, aout);
    gemm_bt2<<<dim3(1024 / 128, 4096 / 64), 256, 0, stream>>>(aout, WoT, bout, out, 4096, 1024, 1024);
}

// Round 8
// 191.169 us; speedup vs baseline: 1.1313x; 1.0119x over previous
//
#include <hip/hip_runtime.h>

typedef unsigned short U16;
typedef __bf16 bf16x8 __attribute__((ext_vector_type(8)));
typedef float f32x4 __attribute__((ext_vector_type(4)));
typedef float f32x16 __attribute__((ext_vector_type(16)));

__device__ inline float b2f(U16 u) {
    union { unsigned int i; float f; } v;
    v.i = ((unsigned int)u) << 16;
    return v.f;
}
__device__ inline U16 f2b(float f) {
    union { float f; unsigned int u; } v;
    v.f = f;
    unsigned int r = (v.u + 0x7fffu + ((v.u >> 16) & 1u)) >> 16;
    return (U16)r;
}

// pack two f32 -> two bf16 in one u32 (RNE, same as f2b)
__device__ inline unsigned cvt_pk(float lo, float hi) {
    unsigned d;
    asm("v_cvt_pk_bf16_f32 %0, %1, %2" : "=v"(d) : "v"(lo), "v"(hi));
    return d;
}
// swap: a[lanes 32-63] <-> b[lanes 0-31]
__device__ inline void plswap(unsigned &a, unsigned &b) {
    asm("v_permlane32_swap_b32 %0, %1" : "+v"(a), "+v"(b));
}

// async global->LDS, 16B per lane (LDS dest = wave-uniform base + lane*16)
__device__ inline void gld16(const void* g, void* l) {
    __builtin_amdgcn_global_load_lds(
        (const __attribute__((address_space(1))) void*)g,
        (__attribute__((address_space(3))) void*)l, 16, 0, 0);
}

// ------- prep: LN (blocks 0..4095) + two weight transposes, ONE launch -----
__global__ __launch_bounds__(256) void prep_kernel(const float* __restrict__ x,
                                                   const float* __restrict__ gamma,
                                                   const float* __restrict__ beta,
                                                   U16* __restrict__ xn,
                                                   const float* __restrict__ Wqkv,
                                                   U16* __restrict__ WqT,
                                                   const float* __restrict__ Wout,
                                                   U16* __restrict__ WoT) {
    int p = blockIdx.x;
    int t = threadIdx.x;
    if (p < 4096) {
        // ---- LayerNorm row p: fp32 -> bf16 ----
        int row = p;
        float4 raw = ((const float4*)(x + (size_t)row * 1024))[t];
        float v[4] = { raw.x, raw.y, raw.z, raw.w };
        float s = v[0] + v[1] + v[2] + v[3];
        float s2 = v[0] * v[0] + v[1] * v[1] + v[2] * v[2] + v[3] * v[3];
#pragma unroll
        for (int off = 32; off >= 1; off >>= 1) {
            s  += __shfl_xor(s,  off);
            s2 += __shfl_xor(s2, off);
        }
        __shared__ float red[8];
        if ((t & 63) == 0) { red[(t >> 6) * 2] = s; red[(t >> 6) * 2 + 1] = s2; }
        __syncthreads();
        float S  = red[0] + red[2] + red[4] + red[6];
        float S2 = red[1] + red[3] + red[5] + red[7];
        float mu = S * (1.0f / 1024.0f);
        float var = S2 * (1.0f / 1024.0f) - mu * mu;
        float rstd = rsqrtf(var + 1e-5f);
        float4 g4 = ((const float4*)gamma)[t];
        float4 b4 = ((const float4*)beta)[t];
        ushort4 o;
        o.x = f2b((v[0] - mu) * rstd * g4.x + b4.x);
        o.y = f2b((v[1] - mu) * rstd * g4.y + b4.y);
        o.z = f2b((v[2] - mu) * rstd * g4.z + b4.z);
        o.w = f2b((v[3] - mu) * rstd * g4.w + b4.w);
        ((ushort4*)(xn + (size_t)row * 1024))[t] = o;
        return;
    }
    // ---- transpose + f2b: out[c][r] = bf16(in[r][c]) ----
    p -= 4096;
    const float* in; U16* out; int C, tilesx;
    if (p < 3072) { in = Wqkv; out = WqT; C = 3072; tilesx = 96; }
    else { p -= 3072; in = Wout; out = WoT; C = 1024; tilesx = 32; }
    const int R = 1024;
    int c0 = (p % tilesx) * 32, r0 = (p / tilesx) * 32;
    int tx = t & 31, ty = t >> 5;   // 32 x 8
    __shared__ float tile[32][33];
#pragma unroll
    for (int i = 0; i < 32; i += 8)
        tile[ty + i][tx] = in[(size_t)(r0 + ty + i) * C + c0 + tx];
    __syncthreads();
#pragma unroll
    for (int i = 0; i < 32; i += 8)
        out[(size_t)(c0 + ty + i) * R + r0 + tx] = f2b(tile[tx][ty + i]);
}

// ------ GEMM1: 256x256 tile, BK=64, 8 waves, counted-vmcnt pipeline (T3+T4).
// Proven in r7 (passed, part of 193.4us total). See r5/r7 notes for the
// vmcnt ledger and oct swizzle derivation.
__global__ __launch_bounds__(512) void gemm256(const U16* __restrict__ A,
                                               const U16* __restrict__ Bt,
                                               U16* __restrict__ C,
                                               U16* __restrict__ vT,
                                               int M, int N, int K) {
    __shared__ __align__(16) U16 As[2][2][128 * 64];
    __shared__ __align__(16) U16 Bs[2][2][128 * 64];
    const int p = blockIdx.x;
    const int xcd = p & 7, sl = p >> 3;              // sl in 0..23
    const int by = xcd * 2 + (sl >= 12 ? 1 : 0);
    const int bx = (sl >= 12) ? (sl - 12) : sl;
    const int m0 = by * 256, n0 = bx * 256;
    const int t = threadIdx.x;
    const int wave = t >> 6, lane = t & 63, l15 = lane & 15, quad = lane >> 4;
    const int wm = wave >> 2, wn = wave & 3;

    f32x4 acc[8][4];
#pragma unroll
    for (int i = 0; i < 8; i++)
#pragma unroll
        for (int j = 0; j < 4; j++)
            acc[i][j] = (f32x4){0.f, 0.f, 0.f, 0.f};

    const int c0 = t, c1 = 512 + t;
    const int sr0 = c0 >> 3, so0 = (c0 & 7) ^ (sr0 & 7);
    const int sr1 = c1 >> 3, so1 = (c1 & 7) ^ (sr1 & 7);
    const U16* Ag0 = A + (size_t)(m0 + sr0) * K + so0 * 8;
    const U16* Ag1 = A + (size_t)(m0 + sr1) * K + so1 * 8;
    const U16* Bg0 = Bt + (size_t)(n0 + sr0) * K + so0 * 8;
    const U16* Bg1 = Bt + (size_t)(n0 + sr1) * K + so1 * 8;
    const size_t hstep = (size_t)128 * K;           // +128 rows

    auto stA = [&](int kt, U16* d0, U16* d1) {      // 4 loads
        gld16(Ag0 + kt * 64, d0 + c0 * 8);
        gld16(Ag1 + kt * 64, d0 + c1 * 8);
        gld16(Ag0 + hstep + kt * 64, d1 + c0 * 8);
        gld16(Ag1 + hstep + kt * 64, d1 + c1 * 8);
    };
    auto stB = [&](int kt, U16* d0, U16* d1) {      // 4 loads
        gld16(Bg0 + kt * 64, d0 + c0 * 8);
        gld16(Bg1 + kt * 64, d0 + c1 * 8);
        gld16(Bg0 + hstep + kt * 64, d1 + c0 * 8);
        gld16(Bg1 + hstep + kt * 64, d1 + c1 * 8);
    };

    const int slot0 = quad ^ (l15 & 7);
    const int slot1 = (4 + quad) ^ (l15 & 7);
    const int aoff0 = l15 * 64 + slot0 * 8, aoff1 = l15 * 64 + slot1 * 8;
    const int bbase = (wn & 1) * 64 * 64;
    const int boff0 = bbase + aoff0, boff1 = bbase + aoff1;
    const int nk = K >> 6;

    auto ktile = [&](const U16* Ac0, const U16* Ac1, const U16* Bc0, const U16* Bc1,
                     U16* An0, U16* An1, U16* Bn0, U16* Bn1, int kt) {
        const bool nx = (kt + 1) < nk;
        if (nx) {
            stA(kt + 1, An0, An1);
            asm volatile("s_waitcnt vmcnt(4)" ::: "memory");
        } else {
            asm volatile("s_waitcnt vmcnt(0)" ::: "memory");
        }
        __builtin_amdgcn_s_barrier();
        asm volatile("" ::: "memory");
        const U16* Ah = wm ? Ac1 : Ac0;
        const U16* Bh = (wn & 2) ? Bc1 : Bc0;
        bf16x8 bfr[4][2], af[4][2];
#pragma unroll
        for (int j = 0; j < 4; j++) {
            bfr[j][0] = *(const bf16x8*)&Bh[j * 16 * 64 + boff0];
            bfr[j][1] = *(const bf16x8*)&Bh[j * 16 * 64 + boff1];
        }
#pragma unroll
        for (int i = 0; i < 4; i++) {
            af[i][0] = *(const bf16x8*)&Ah[i * 16 * 64 + aoff0];
            af[i][1] = *(const bf16x8*)&Ah[i * 16 * 64 + aoff1];
        }
        if (nx) stB(kt + 1, Bn0, Bn1);
        __builtin_amdgcn_s_setprio(1);
#pragma unroll
        for (int i = 0; i < 4; i++)
#pragma unroll
            for (int j = 0; j < 4; j++) {
                acc[i][j] = __builtin_amdgcn_mfma_f32_16x16x32_bf16(af[i][0], bfr[j][0], acc[i][j], 0, 0, 0);
                acc[i][j] = __builtin_amdgcn_mfma_f32_16x16x32_bf16(af[i][1], bfr[j][1], acc[i][j], 0, 0, 0);
            }
        __builtin_amdgcn_s_setprio(0);
        asm volatile("" ::: "memory");
        __builtin_amdgcn_s_barrier();
        asm volatile("" ::: "memory");
#pragma unroll
        for (int i = 0; i < 4; i++) {
            af[i][0] = *(const bf16x8*)&Ah[(4 + i) * 16 * 64 + aoff0];
            af[i][1] = *(const bf16x8*)&Ah[(4 + i) * 16 * 64 + aoff1];
        }
        __builtin_amdgcn_s_setprio(1);
#pragma unroll
        for (int i = 0; i < 4; i++)
#pragma unroll
            for (int j = 0; j < 4; j++) {
                acc[4 + i][j] = __builtin_amdgcn_mfma_f32_16x16x32_bf16(af[i][0], bfr[j][0], acc[4 + i][j], 0, 0, 0);
                acc[4 + i][j] = __builtin_amdgcn_mfma_f32_16x16x32_bf16(af[i][1], bfr[j][1], acc[4 + i][j], 0, 0, 0);
            }
        __builtin_amdgcn_s_setprio(0);
        asm volatile("" ::: "memory");
        __builtin_amdgcn_s_barrier();
        asm volatile("" ::: "memory");
    };

    stA(0, &As[0][0][0], &As[0][1][0]);
    stB(0, &Bs[0][0][0], &Bs[0][1][0]);
    asm volatile("s_waitcnt vmcnt(0)" ::: "memory");
    __builtin_amdgcn_s_barrier();
    asm volatile("" ::: "memory");

    for (int kt = 0; kt < nk; kt += 2) {
        ktile(&As[0][0][0], &As[0][1][0], &Bs[0][0][0], &Bs[0][1][0],
              &As[1][0][0], &As[1][1][0], &Bs[1][0][0], &Bs[1][1][0], kt);
        ktile(&As[1][0][0], &As[1][1][0], &Bs[1][0][0], &Bs[1][1][0],
              &As[0][0][0], &As[0][1][0], &Bs[0][0][0], &Bs[0][1][0], kt + 1);
    }

    if (vT && n0 >= 2048) {
#pragma unroll
        for (int i = 0; i < 8; i++) {
#pragma unroll
            for (int j = 0; j < 4; j++) {
                int col = n0 + wn * 64 + j * 16 + l15 - 2048;
                int hh = col >> 6, dd = col & 63;
                int row0 = m0 + wm * 128 + i * 16 + quad * 4;
                int bb = row0 >> 11, nn = row0 & 2047;
                ushort4 st;
                st.x = f2b(acc[i][j][0]); st.y = f2b(acc[i][j][1]);
                st.z = f2b(acc[i][j][2]); st.w = f2b(acc[i][j][3]);
                *(ushort4*)&vT[((((size_t)bb * 16) + hh) * 64 + dd) * 2048 + nn] = st;
            }
        }
        return;
    }
#pragma unroll
    for (int i = 0; i < 8; i++) {
#pragma unroll
        for (int j = 0; j < 4; j++) {
            int col = n0 + wn * 64 + j * 16 + l15;
#pragma unroll
            for (int r = 0; r < 4; r++) {
                int row = m0 + wm * 128 + i * 16 + quad * 4 + r;
                C[(size_t)row * N + col] = f2b(acc[i][j][r]);
            }
        }
    }
}

// ------ GEMM2: 64x128 tile, BK=64, counted-vmcnt pipeline (gemm256 pattern).
// Old version: 32 k-iters x 2 full __syncthreads drains (vmcnt(0)+lgkm(0))
// per block. New: 16 K-tiles x 2 raw s_barrier, A(t+1) loads stay IN FLIGHT
// across the consume barrier. vmcnt ledger (per wave): entry = 6 outstanding
// [A(t) 2, B(t) 4]; issue A(t+1) -> 8; vmcnt(2) retires exactly A(t)+B(t).
// Buf-reuse safe: stA(t+2) (into the buffer read at tile t) is issued at the
// start of ktile(t+1), after tile t's end-barrier, by which point every
// wave's ds_reads of that buffer completed (lgkm-waited before their MFMAs).
// Oct swizzle identical to gemm256/attn.
__global__ __launch_bounds__(256) void gemm_bt2(const U16* __restrict__ A,
                                                const U16* __restrict__ Bt,
                                                const float* __restrict__ bias,
                                                float* __restrict__ C,
                                                int M, int N, int K) {
    __shared__ __align__(16) U16 As[2][64 * 64];
    __shared__ __align__(16) U16 Bs[2][128 * 64];
    const int m0 = blockIdx.y * 64, n0 = blockIdx.x * 128;
    const int t = threadIdx.x;
    const int wave = t >> 6, lane = t & 63, l15 = lane & 15, quad = lane >> 4;
    const int wm = (wave >> 1) * 32, wn = (wave & 1) * 64;

    f32x4 acc[2][4];
#pragma unroll
    for (int i = 0; i < 2; i++)
#pragma unroll
        for (int j = 0; j < 4; j++)
            acc[i][j] = (f32x4){0.f, 0.f, 0.f, 0.f};

    // A: 512 chunks (2/thread); B: 1024 chunks (4/thread)
    const int cA0 = t, cA1 = 256 + t;
    const int srA0 = cA0 >> 3, soA0 = (cA0 & 7) ^ (srA0 & 7);
    const int srA1 = cA1 >> 3, soA1 = (cA1 & 7) ^ (srA1 & 7);
    const U16* AgA0 = A + (size_t)(m0 + srA0) * K + soA0 * 8;
    const U16* AgA1 = A + (size_t)(m0 + srA1) * K + soA1 * 8;
    const int cB0 = t, cB1 = 256 + t, cB2 = 512 + t, cB3 = 768 + t;
    const int srB0 = cB0 >> 3, soB0 = (cB0 & 7) ^ (srB0 & 7);
    const int srB1 = cB1 >> 3, soB1 = (cB1 & 7) ^ (srB1 & 7);
    const int srB2 = cB2 >> 3, soB2 = (cB2 & 7) ^ (srB2 & 7);
    const int srB3 = cB3 >> 3, soB3 = (cB3 & 7) ^ (srB3 & 7);
    const U16* BgB0 = Bt + (size_t)(n0 + srB0) * K + soB0 * 8;
    const U16* BgB1 = Bt + (size_t)(n0 + srB1) * K + soB1 * 8;
    const U16* BgB2 = Bt + (size_t)(n0 + srB2) * K + soB2 * 8;
    const U16* BgB3 = Bt + (size_t)(n0 + srB3) * K + soB3 * 8;

    auto stAf = [&](int kt, U16* d) {               // 2 loads
        gld16(AgA0 + kt * 64, d + cA0 * 8);
        gld16(AgA1 + kt * 64, d + cA1 * 8);
    };
    auto stBf = [&](int kt, U16* d) {               // 4 loads
        gld16(BgB0 + kt * 64, d + cB0 * 8);
        gld16(BgB1 + kt * 64, d + cB1 * 8);
        gld16(BgB2 + kt * 64, d + cB2 * 8);
        gld16(BgB3 + kt * 64, d + cB3 * 8);
    };

    // frag-read slot offsets (elements): k 0..31 -> oct quad, k 32..63 -> 4+quad
    const int as0 = (quad ^ (l15 & 7)) * 8;
    const int as1 = ((4 + quad) ^ (l15 & 7)) * 8;
    const int nk = K >> 6;                          // 16

    auto ktile = [&](const U16* Ac, const U16* Bc, U16* An, U16* Bn, int kt) {
        const bool nx = (kt + 1) < nk;
        if (nx) {
            stAf(kt + 1, An);
            asm volatile("s_waitcnt vmcnt(2)" ::: "memory");
        } else {
            asm volatile("s_waitcnt vmcnt(0)" ::: "memory");
        }
        __builtin_amdgcn_s_barrier();
        asm volatile("" ::: "memory");
        bf16x8 af[2][2], bfr[4][2];
#pragma unroll
        for (int i = 0; i < 2; i++) {
            af[i][0] = *(const bf16x8*)&Ac[(wm + i * 16 + l15) * 64 + as0];
            af[i][1] = *(const bf16x8*)&Ac[(wm + i * 16 + l15) * 64 + as1];
        }
#pragma unroll
        for (int j = 0; j < 4; j++) {
            bfr[j][0] = *(const bf16x8*)&Bc[(wn + j * 16 + l15) * 64 + as0];
            bfr[j][1] = *(const bf16x8*)&Bc[(wn + j * 16 + l15) * 64 + as1];
        }
        if (nx) stBf(kt + 1, Bn);
        __builtin_amdgcn_s_setprio(1);
#pragma unroll
        for (int i = 0; i < 2; i++)
#pragma unroll
            for (int j = 0; j < 4; j++) {
                acc[i][j] = __builtin_amdgcn_mfma_f32_16x16x32_bf16(af[i][0], bfr[j][0], acc[i][j], 0, 0, 0);
                acc[i][j] = __builtin_amdgcn_mfma_f32_16x16x32_bf16(af[i][1], bfr[j][1], acc[i][j], 0, 0, 0);
            }
        __builtin_amdgcn_s_setprio(0);
        asm volatile("" ::: "memory");
        __builtin_amdgcn_s_barrier();
        asm volatile("" ::: "memory");
    };

    stAf(0, &As[0][0]);
    stBf(0, &Bs[0][0]);
    asm volatile("s_waitcnt vmcnt(0)" ::: "memory");
    __builtin_amdgcn_s_barrier();
    asm volatile("" ::: "memory");

    for (int kt = 0; kt < nk; kt += 2) {
        ktile(&As[0][0], &Bs[0][0], &As[1][0], &Bs[1][0], kt);
        ktile(&As[1][0], &Bs[1][0], &As[0][0], &Bs[0][0], kt + 1);
    }

#pragma unroll
    for (int i = 0; i < 2; i++) {
#pragma unroll
        for (int j = 0; j < 4; j++) {
            int col = n0 + wn + j * 16 + l15;
            float bv = bias[col];
#pragma unroll
            for (int r = 0; r < 4; r++) {
                int row = m0 + wm + i * 16 + quad * 4 + r;
                C[(size_t)row * N + col] = acc[i][j][r] + bv;
            }
        }
    }
}

// ---- MFMA flash attention, in-register softmax, chain-broken schedule.
//
// r7 counters: MfmaUtil 24.6 / VALUBusy 38.5, 2 waves/SIMD — dependency-
// bound, neither pipe saturated. Per tile the wave ran the serial chain
// QK0 -> SM0 -> PV0 -> QK1 -> SM1 -> PV1. This version breaks it:
//  * QK1 hoisted before SM0: both QK blocks issue back-to-back; QK1
//    executes in the MFMA pipe UNDER SM0's VALU work.
//  * PV accumulator split (oaccA = k-slot 0, oaccB = k-slot 1; summed in
//    the epilogue): halves the per-tile PV dependency chain. fp32 reorder
//    only. VGPR cost ~+50, free at 2 waves/SIMD (budget 256).
// Everything else unchanged from the proven r5/r7 kernel (oct swizzle,
// Q pre-scale, XCD mapping, 1-barrier-per-tile dbuf staging).
__global__ __launch_bounds__(256) void attn_kernel(const U16* __restrict__ qkv,
                                                   const U16* __restrict__ vT,
                                                   U16* __restrict__ attn_out) {
    const int p = blockIdx.x;                    // 0..511
    const int xcd = p & 7;
    const int slot = p >> 3;                     // 0..63 within XCD
    const int bh = ((slot & 3) << 3) | xcd;      // bh & 7 == XCD id
    const int qt = slot >> 2;                    // 0..15, 128 q-rows per block
    const int b = bh >> 4, h = bh & 15;
    const int t = threadIdx.x;
    const int wave = t >> 6, lane = t & 63;
    const int l31 = lane & 31, hi = lane >> 5;
    const float sc2 = 0.125f * 1.44269504089f;  // scale * log2(e)

    __shared__ __align__(16) U16 Kt[2][64 * 64];    // [key][d-swizzled]
    __shared__ __align__(16) U16 Vt[2][64 * 64];    // [d][key-swizzled]

    const size_t base = (size_t)(b * 2048) * 3072;
    const U16* vTbh = vT + ((size_t)(b * 16 + h) * 64) * 2048;

    // Q fragments, pre-scaled by sc2
    bf16x8 qf[4];
    {
        int qrow = qt * 128 + wave * 32 + l31;
        const U16* qp = qkv + base + (size_t)qrow * 3072 + h * 64 + hi * 8;
#pragma unroll
        for (int s = 0; s < 4; s++) {
            union { bf16x8 v; U16 u[8]; } a;
            a.v = *(const bf16x8*)&qp[s * 16];
#pragma unroll
            for (int e = 0; e < 8; e++) a.u[e] = f2b(b2f(a.u[e]) * sc2);
            qf[s] = a.v;
        }
    }

    float l4[4] = { 0.f, 0.f, 0.f, 0.f };
    f32x16 oaccA[2], oaccB[2];  // O^T split by k-slot; summed in epilogue
#pragma unroll
    for (int db = 0; db < 2; db++)
#pragma unroll
        for (int r = 0; r < 16; r++) {
            oaccA[db][r] = 0.0f;
            oaccB[db][r] = 0.0f;
        }

    const int c0 = t, c1 = 256 + t;
    const int row0 = c0 >> 3, oct0 = (c0 & 7) ^ (row0 & 7);
    const int row1 = c1 >> 3, oct1 = (c1 & 7) ^ (row1 & 7);

    gld16(&qkv[base + (size_t)row0 * 3072 + 1024 + h * 64 + oct0 * 8], &Kt[0][c0 * 8]);
    gld16(&qkv[base + (size_t)row1 * 3072 + 1024 + h * 64 + oct1 * 8], &Kt[0][c1 * 8]);
    gld16(&vTbh[(size_t)row0 * 2048 + oct0 * 8], &Vt[0][c0 * 8]);
    gld16(&vTbh[(size_t)row1 * 2048 + oct1 * 8], &Vt[0][c1 * 8]);
    __syncthreads();

    auto step = [&](const U16* KtC, const U16* VtC, U16* KtN, U16* VtN, int nt) {
        gld16(&qkv[base + (size_t)(nt * 64 + row0) * 3072 + 1024 + h * 64 + oct0 * 8], &KtN[c0 * 8]);
        gld16(&qkv[base + (size_t)(nt * 64 + row1) * 3072 + 1024 + h * 64 + oct1 * 8], &KtN[c1 * 8]);
        gld16(&vTbh[(size_t)row0 * 2048 + nt * 64 + oct0 * 8], &VtN[c0 * 8]);
        gld16(&vTbh[(size_t)row1 * 2048 + nt * 64 + oct1 * 8], &VtN[c1 * 8]);

        // ---- all K and V frags up front ----
        bf16x8 kf[2][4];
#pragma unroll
        for (int kb = 0; kb < 2; kb++)
#pragma unroll
            for (int s = 0; s < 4; s++)
                kf[kb][s] = *(const bf16x8*)&KtC[(kb * 32 + l31) * 64 +
                                                 (((s * 2 + hi) ^ (l31 & 7)) * 8)];
        bf16x8 vfr[2][2][2];
#pragma unroll
        for (int kb = 0; kb < 2; kb++)
#pragma unroll
            for (int db = 0; db < 2; db++)
#pragma unroll
                for (int s = 0; s < 2; s++)
                    vfr[kb][db][s] = *(const bf16x8*)&VtC[(db * 32 + l31) * 64 +
                                                          (((kb * 4 + s * 2 + hi) ^ (l31 & 7)) * 8)];

        // ---- both QK^T blocks back-to-back (QK1 runs under SM0's VALU) ----
        f32x16 stA = {0.f, 0.f, 0.f, 0.f, 0.f, 0.f, 0.f, 0.f,
                      0.f, 0.f, 0.f, 0.f, 0.f, 0.f, 0.f, 0.f};
        f32x16 stB = stA;
        __builtin_amdgcn_s_setprio(1);
#pragma unroll
        for (int s = 0; s < 4; s++)
            stA = __builtin_amdgcn_mfma_f32_32x32x16_bf16(kf[0][s], qf[s], stA, 0, 0, 0);
#pragma unroll
        for (int s = 0; s < 4; s++)
            stB = __builtin_amdgcn_mfma_f32_32x32x16_bf16(kf[1][s], qf[s], stB, 0, 0, 0);
        __builtin_amdgcn_s_setprio(0);

        // ---- kb=0: softmax + pack + PV (split accumulators) ----
        {
            float pe[16];
#pragma unroll
            for (int r = 0; r < 16; r++) {
                pe[r] = __builtin_amdgcn_exp2f(stA[r]);
                l4[r & 3] += pe[r];
            }
            unsigned p01 = cvt_pk(pe[0], pe[1]), p23 = cvt_pk(pe[2], pe[3]);
            unsigned p45 = cvt_pk(pe[4], pe[5]), p67 = cvt_pk(pe[6], pe[7]);
            plswap(p01, p45); plswap(p23, p67);
            union { unsigned u[4]; bf16x8 v; } pw0;
            pw0.u[0] = p01; pw0.u[1] = p23; pw0.u[2] = p45; pw0.u[3] = p67;
            unsigned q01 = cvt_pk(pe[8], pe[9]), q23 = cvt_pk(pe[10], pe[11]);
            unsigned q45 = cvt_pk(pe[12], pe[13]), q67 = cvt_pk(pe[14], pe[15]);
            plswap(q01, q45); plswap(q23, q67);
            union { unsigned u[4]; bf16x8 v; } pw1;
            pw1.u[0] = q01; pw1.u[1] = q23; pw1.u[2] = q45; pw1.u[3] = q67;
            __builtin_amdgcn_s_setprio(1);
            oaccA[0] = __builtin_amdgcn_mfma_f32_32x32x16_bf16(vfr[0][0][0], pw0.v, oaccA[0], 0, 0, 0);
            oaccA[1] = __builtin_amdgcn_mfma_f32_32x32x16_bf16(vfr[0][1][0], pw0.v, oaccA[1], 0, 0, 0);
            oaccB[0] = __builtin_amdgcn_mfma_f32_32x32x16_bf16(vfr[0][0][1], pw1.v, oaccB[0], 0, 0, 0);
            oaccB[1] = __builtin_amdgcn_mfma_f32_32x32x16_bf16(vfr[0][1][1], pw1.v, oaccB[1], 0, 0, 0);
            __builtin_amdgcn_s_setprio(0);
        }
        // ---- kb=1: softmax + pack + PV ----
        {
            float pe[16];
#pragma unroll
            for (int r = 0; r < 16; r++) {
                pe[r] = __builtin_amdgcn_exp2f(stB[r]);
                l4[r & 3] += pe[r];
            }
            unsigned p01 = cvt_pk(pe[0], pe[1]), p23 = cvt_pk(pe[2], pe[3]);
            unsigned p45 = cvt_pk(pe[4], pe[5]), p67 = cvt_pk(pe[6], pe[7]);
            plswap(p01, p45); plswap(p23, p67);
            union { unsigned u[4]; bf16x8 v; } pw0;
            pw0.u[0] = p01; pw0.u[1] = p23; pw0.u[2] = p45; pw0.u[3] = p67;
            unsigned q01 = cvt_pk(pe[8], pe[9]), q23 = cvt_pk(pe[10], pe[11]);
            unsigned q45 = cvt_pk(pe[12], pe[13]), q67 = cvt_pk(pe[14], pe[15]);
            plswap(q01, q45); plswap(q23, q67);
            union { unsigned u[4]; bf16x8 v; } pw1;
            pw1.u[0] = q01; pw1.u[1] = q23; pw1.u[2] = q45; pw1.u[3] = q67;
            __builtin_amdgcn_s_setprio(1);
            oaccA[0] = __builtin_amdgcn_mfma_f32_32x32x16_bf16(vfr[1][0][0], pw0.v, oaccA[0], 0, 0, 0);
            oaccA[1] = __builtin_amdgcn_mfma_f32_32x32x16_bf16(vfr[1][1][0], pw0.v, oaccA[1], 0, 0, 0);
            oaccB[0] = __builtin_amdgcn_mfma_f32_32x32x16_bf16(vfr[1][0][1], pw1.v, oaccB[0], 0, 0, 0);
            oaccB[1] = __builtin_amdgcn_mfma_f32_32x32x16_bf16(vfr[1][1][1], pw1.v, oaccB[1], 0, 0, 0);
            __builtin_amdgcn_s_setprio(0);
        }
        __syncthreads();
    };

    for (int kt2 = 0; kt2 < 16; kt2++) {
        step(&Kt[0][0], &Vt[0][0], &Kt[1][0], &Vt[1][0], 2 * kt2 + 1);
        step(&Kt[1][0], &Vt[1][0], &Kt[0][0], &Vt[0][0], (2 * kt2 + 2) & 31);
    }

    float l_acc = (l4[0] + l4[1]) + (l4[2] + l4[3]);
    float lt = l_acc + __shfl_xor(l_acc, 32);
    float inv = 1.0f / lt;
    int qrow = b * 2048 + qt * 128 + wave * 32 + l31;
#pragma unroll
    for (int db = 0; db < 2; db++) {
        f32x16 o = oaccA[db] + oaccB[db];
#pragma unroll
        for (int g = 0; g < 4; g++) {
            ushort4 stv;
            stv.x = f2b(o[g * 4 + 0] * inv);
            stv.y = f2b(o[g * 4 + 1] * inv);
            stv.z = f2b(o[g * 4 + 2] * inv);
            stv.w = f2b(o[g * 4 + 3] * inv);
            int col = h * 64 + db * 32 + g * 8 + hi * 4;
            *(ushort4*)&attn_out[(size_t)qrow * 1024 + col] = stv;
        }
    }
}

extern "C" void kernel_launch(void* const* d_in, const int* in_sizes, int n_in,
                              void* d_out, int out_size, void* d_ws, size_t ws_size,
                              hipStream_t stream) {
    (void)in_sizes; (void)n_in; (void)out_size; (void)ws_size;
    const float* x    = (const float*)d_in[0];
    const float* g    = (const float*)d_in[1];
    const float* be   = (const float*)d_in[2];
    const float* Wqkv = (const float*)d_in[3];
    const float* Wout = (const float*)d_in[4];
    const float* bout = (const float*)d_in[5];
    float* out = (float*)d_out;   // reference output dtype is fp32
    char* ws = (char*)d_ws;

    U16* xn   = (U16*)(ws);                          // 8 MB, reused as aout
    U16* qkv  = (U16*)(ws + (size_t)(8u  << 20));    // 24 MB (V third unused)
    U16* WqT  = (U16*)(ws + (size_t)(32u << 20));    // 6 MB
    U16* WoT  = (U16*)(ws + (size_t)(38u << 20));    // 2 MB
    U16* vT   = (U16*)(ws + (size_t)(40u << 20));    // 8 MB: V transposed
    U16* aout = xn;  // xn dead after GEMM1

    prep_kernel<<<8192, 256, 0, stream>>>(x, g, be, xn, Wqkv, WqT, Wout, WoT);
    gemm256<<<192, 512, 0, stream>>>(xn, WqT, qkv, vT, 4096, 3072, 1024);
    attn_kernel<<<512, 256, 0, stream>>>(qkv, vT, aout);
    gemm_bt2<<<dim3(1024 / 128, 4096 / 64), 256, 0, stream>>>(aout, WoT, bout, out, 4096, 1024, 1024);
}

// Round 9
// 180.983 us; speedup vs baseline: 1.1950x; 1.0563x over previous
//
#include <hip/hip_runtime.h>

typedef unsigned short U16;
typedef __bf16 bf16x8 __attribute__((ext_vector_type(8)));
typedef float f32x4 __attribute__((ext_vector_type(4)));
typedef float f32x16 __attribute__((ext_vector_type(16)));

__device__ inline float b2f(U16 u) {
    union { unsigned int i; float f; } v;
    v.i = ((unsigned int)u) << 16;
    return v.f;
}
__device__ inline U16 f2b(float f) {
    union { float f; unsigned int u; } v;
    v.f = f;
    unsigned int r = (v.u + 0x7fffu + ((v.u >> 16) & 1u)) >> 16;
    return (U16)r;
}

// pack two f32 -> two bf16 in one u32 (RNE, same as f2b)
__device__ inline unsigned cvt_pk(float lo, float hi) {
    unsigned d;
    asm("v_cvt_pk_bf16_f32 %0, %1, %2" : "=v"(d) : "v"(lo), "v"(hi));
    return d;
}
// swap: a[lanes 32-63] <-> b[lanes 0-31]
__device__ inline void plswap(unsigned &a, unsigned &b) {
    asm("v_permlane32_swap_b32 %0, %1" : "+v"(a), "+v"(b));
}

// async global->LDS, 16B per lane (LDS dest = wave-uniform base + lane*16)
__device__ inline void gld16(const void* g, void* l) {
    __builtin_amdgcn_global_load_lds(
        (const __attribute__((address_space(1))) void*)g,
        (__attribute__((address_space(3))) void*)l, 16, 0, 0);
}

// ------- prep: LN (blocks 0..4095) + two weight transposes, ONE launch -----
__global__ __launch_bounds__(256) void prep_kernel(const float* __restrict__ x,
                                                   const float* __restrict__ gamma,
                                                   const float* __restrict__ beta,
                                                   U16* __restrict__ xn,
                                                   const float* __restrict__ Wqkv,
                                                   U16* __restrict__ WqT,
                                                   const float* __restrict__ Wout,
                                                   U16* __restrict__ WoT) {
    int p = blockIdx.x;
    int t = threadIdx.x;
    if (p < 4096) {
        // ---- LayerNorm row p: fp32 -> bf16 ----
        int row = p;
        float4 raw = ((const float4*)(x + (size_t)row * 1024))[t];
        float v[4] = { raw.x, raw.y, raw.z, raw.w };
        float s = v[0] + v[1] + v[2] + v[3];
        float s2 = v[0] * v[0] + v[1] * v[1] + v[2] * v[2] + v[3] * v[3];
#pragma unroll
        for (int off = 32; off >= 1; off >>= 1) {
            s  += __shfl_xor(s,  off);
            s2 += __shfl_xor(s2, off);
        }
        __shared__ float red[8];
        if ((t & 63) == 0) { red[(t >> 6) * 2] = s; red[(t >> 6) * 2 + 1] = s2; }
        __syncthreads();
        float S  = red[0] + red[2] + red[4] + red[6];
        float S2 = red[1] + red[3] + red[5] + red[7];
        float mu = S * (1.0f / 1024.0f);
        float var = S2 * (1.0f / 1024.0f) - mu * mu;
        float rstd = rsqrtf(var + 1e-5f);
        float4 g4 = ((const float4*)gamma)[t];
        float4 b4 = ((const float4*)beta)[t];
        ushort4 o;
        o.x = f2b((v[0] - mu) * rstd * g4.x + b4.x);
        o.y = f2b((v[1] - mu) * rstd * g4.y + b4.y);
        o.z = f2b((v[2] - mu) * rstd * g4.z + b4.z);
        o.w = f2b((v[3] - mu) * rstd * g4.w + b4.w);
        ((ushort4*)(xn + (size_t)row * 1024))[t] = o;
        return;
    }
    // ---- transpose + f2b: out[c][r] = bf16(in[r][c]) ----
    p -= 4096;
    const float* in; U16* out; int C, tilesx;
    if (p < 3072) { in = Wqkv; out = WqT; C = 3072; tilesx = 96; }
    else { p -= 3072; in = Wout; out = WoT; C = 1024; tilesx = 32; }
    const int R = 1024;
    int c0 = (p % tilesx) * 32, r0 = (p / tilesx) * 32;
    int tx = t & 31, ty = t >> 5;   // 32 x 8
    __shared__ float tile[32][33];
#pragma unroll
    for (int i = 0; i < 32; i += 8)
        tile[ty + i][tx] = in[(size_t)(r0 + ty + i) * C + c0 + tx];
    __syncthreads();
#pragma unroll
    for (int i = 0; i < 32; i += 8)
        out[(size_t)(c0 + ty + i) * R + r0 + tx] = f2b(tile[tx][ty + i]);
}

// ------ GEMM1: 256x192 tile, BK=64, 8 waves, counted-vmcnt pipeline.
//
// r8 post-mortem: the 256x256 version's grid was 16x12 = 192 blocks = 0.75
// blocks/CU — 64 CUs idle, capping at ~875 TF regardless of schedule. This
// retile gives 16 x (3072/192) = 256 blocks = FULL CHIP at the same 1
// block/CU (LDS 112 KB = A 64 + B 48). Same proven schedule as r7's gemm256:
//   issue stA(t+1) [4 loads]; s_waitcnt vmcnt(4); s_barrier
//     (ledger: entry 7 = A(t)4+B(t)3; +4 = 11; retire 7 oldest = tile t)
//   P0: ds_read B(j=0..2) + A(i=0..3); issue stB(t+1) [3 loads]; 24 MFMA
//   s_barrier
//   P1: ds_read A(i=4..7); 24 MFMA; s_barrier
// NEVER vmcnt(0) in the loop. Oct swizzle identical to attn/gemm256.
// 192-wide tiles straddle the col-2048 Q,K|V boundary: 2048 % 16 == 0 and
// j-blocks are 16-aligned, so the vT-vs-C branch is uniform per (wave,j) —
// handled per-j in the epilogue.
// XCD decode: 256 blocks, xcd p&7 owns m-rows {2*xcd, 2*xcd+1} (A panel
// 1 MB in its L2).
__global__ __launch_bounds__(512) void gemm_g1(const U16* __restrict__ A,
                                               const U16* __restrict__ Bt,
                                               U16* __restrict__ C,
                                               U16* __restrict__ vT,
                                               int M, int N, int K) {
    __shared__ __align__(16) U16 As[2][2][128 * 64];   // 64 KB
    __shared__ __align__(16) U16 Bs[2][192 * 64];      // 48 KB
    const int p = blockIdx.x;
    const int xcd = p & 7, sl = p >> 3;              // sl in 0..31
    const int by = xcd * 2 + (sl >> 4);
    const int bx = sl & 15;
    const int m0 = by * 256, n0 = bx * 192;
    const int t = threadIdx.x;
    const int wave = t >> 6, lane = t & 63, l15 = lane & 15, quad = lane >> 4;
    const int wm = wave >> 2, wn = wave & 3;

    f32x4 acc[8][3];
#pragma unroll
    for (int i = 0; i < 8; i++)
#pragma unroll
        for (int j = 0; j < 3; j++)
            acc[i][j] = (f32x4){0.f, 0.f, 0.f, 0.f};

    // A staging: 2048 chunks per 256-row tile (2 halves x 1024), 4/thread
    const int c0 = t, c1 = 512 + t;
    const int sr0 = c0 >> 3, so0 = (c0 & 7) ^ (sr0 & 7);
    const int sr1 = c1 >> 3, so1 = (c1 & 7) ^ (sr1 & 7);
    const U16* Ag0 = A + (size_t)(m0 + sr0) * K + so0 * 8;
    const U16* Ag1 = A + (size_t)(m0 + sr1) * K + so1 * 8;
    const size_t hstep = (size_t)128 * K;           // +128 rows

    // B staging: 1536 chunks per 192-row tile, 3/thread
    const int cb2 = 1024 + t;
    const int sb2 = cb2 >> 3, ob2 = (cb2 & 7) ^ (sb2 & 7);
    const U16* Bg0 = Bt + (size_t)(n0 + sr0) * K + so0 * 8;   // chunk t
    const U16* Bg1 = Bt + (size_t)(n0 + sr1) * K + so1 * 8;   // chunk 512+t
    const U16* Bg2 = Bt + (size_t)(n0 + sb2) * K + ob2 * 8;   // chunk 1024+t

    auto stA = [&](int kt, U16* d0, U16* d1) {      // 4 loads
        gld16(Ag0 + kt * 64, d0 + c0 * 8);
        gld16(Ag1 + kt * 64, d0 + c1 * 8);
        gld16(Ag0 + hstep + kt * 64, d1 + c0 * 8);
        gld16(Ag1 + hstep + kt * 64, d1 + c1 * 8);
    };
    auto stB = [&](int kt, U16* d) {                // 3 loads
        gld16(Bg0 + kt * 64, d + c0 * 8);
        gld16(Bg1 + kt * 64, d + c1 * 8);
        gld16(Bg2 + kt * 64, d + cb2 * 8);
    };

    // frag-read offsets (elements): k 0..31 -> oct quad, k 32..63 -> 4+quad
    const int slot0 = quad ^ (l15 & 7);
    const int slot1 = (4 + quad) ^ (l15 & 7);
    const int aoff0 = l15 * 64 + slot0 * 8, aoff1 = l15 * 64 + slot1 * 8;
    const int boff0 = wn * 48 * 64 + aoff0, boff1 = wn * 48 * 64 + aoff1;
    const int nk = K >> 6;                          // 16

    auto ktile = [&](const U16* Ac0, const U16* Ac1, const U16* Bc,
                     U16* An0, U16* An1, U16* Bn, int kt) {
        const bool nx = (kt + 1) < nk;
        if (nx) {
            stA(kt + 1, An0, An1);
            asm volatile("s_waitcnt vmcnt(4)" ::: "memory");
        } else {
            asm volatile("s_waitcnt vmcnt(0)" ::: "memory");
        }
        __builtin_amdgcn_s_barrier();
        asm volatile("" ::: "memory");
        const U16* Ah = wm ? Ac1 : Ac0;
        bf16x8 bfr[3][2], af[4][2];
#pragma unroll
        for (int j = 0; j < 3; j++) {
            bfr[j][0] = *(const bf16x8*)&Bc[j * 16 * 64 + boff0];
            bfr[j][1] = *(const bf16x8*)&Bc[j * 16 * 64 + boff1];
        }
#pragma unroll
        for (int i = 0; i < 4; i++) {
            af[i][0] = *(const bf16x8*)&Ah[i * 16 * 64 + aoff0];
            af[i][1] = *(const bf16x8*)&Ah[i * 16 * 64 + aoff1];
        }
        if (nx) stB(kt + 1, Bn);
        __builtin_amdgcn_s_setprio(1);
#pragma unroll
        for (int i = 0; i < 4; i++)
#pragma unroll
            for (int j = 0; j < 3; j++) {
                acc[i][j] = __builtin_amdgcn_mfma_f32_16x16x32_bf16(af[i][0], bfr[j][0], acc[i][j], 0, 0, 0);
                acc[i][j] = __builtin_amdgcn_mfma_f32_16x16x32_bf16(af[i][1], bfr[j][1], acc[i][j], 0, 0, 0);
            }
        __builtin_amdgcn_s_setprio(0);
        asm volatile("" ::: "memory");
        __builtin_amdgcn_s_barrier();
        asm volatile("" ::: "memory");
#pragma unroll
        for (int i = 0; i < 4; i++) {
            af[i][0] = *(const bf16x8*)&Ah[(4 + i) * 16 * 64 + aoff0];
            af[i][1] = *(const bf16x8*)&Ah[(4 + i) * 16 * 64 + aoff1];
        }
        __builtin_amdgcn_s_setprio(1);
#pragma unroll
        for (int i = 0; i < 4; i++)
#pragma unroll
            for (int j = 0; j < 3; j++) {
                acc[4 + i][j] = __builtin_amdgcn_mfma_f32_16x16x32_bf16(af[i][0], bfr[j][0], acc[4 + i][j], 0, 0, 0);
                acc[4 + i][j] = __builtin_amdgcn_mfma_f32_16x16x32_bf16(af[i][1], bfr[j][1], acc[4 + i][j], 0, 0, 0);
            }
        __builtin_amdgcn_s_setprio(0);
        asm volatile("" ::: "memory");
        __builtin_amdgcn_s_barrier();
        asm volatile("" ::: "memory");
    };

    // prologue: tile 0 -> buf 0, full drain once
    stA(0, &As[0][0][0], &As[0][1][0]);
    stB(0, &Bs[0][0]);
    asm volatile("s_waitcnt vmcnt(0)" ::: "memory");
    __builtin_amdgcn_s_barrier();
    asm volatile("" ::: "memory");

    for (int kt = 0; kt < nk; kt += 2) {
        ktile(&As[0][0][0], &As[0][1][0], &Bs[0][0],
              &As[1][0][0], &As[1][1][0], &Bs[1][0], kt);
        ktile(&As[1][0][0], &As[1][1][0], &Bs[1][0],
              &As[0][0][0], &As[0][1][0], &Bs[0][0], kt + 1);
    }

    // epilogue: per-j V-vs-C branch (j-blocks are 16-aligned; 2048 % 16 == 0)
#pragma unroll
    for (int j = 0; j < 3; j++) {
        int cb = n0 + wn * 48 + j * 16;
        if (vT && cb >= 2048) {
#pragma unroll
            for (int i = 0; i < 8; i++) {
                int col = cb + l15 - 2048;
                int hh = col >> 6, dd = col & 63;
                int row0 = m0 + wm * 128 + i * 16 + quad * 4;
                int bb = row0 >> 11, nn = row0 & 2047;
                ushort4 st;
                st.x = f2b(acc[i][j][0]); st.y = f2b(acc[i][j][1]);
                st.z = f2b(acc[i][j][2]); st.w = f2b(acc[i][j][3]);
                *(ushort4*)&vT[((((size_t)bb * 16) + hh) * 64 + dd) * 2048 + nn] = st;
            }
        } else {
#pragma unroll
            for (int i = 0; i < 8; i++) {
                int col = cb + l15;
                int row0 = m0 + wm * 128 + i * 16 + quad * 4;
#pragma unroll
                for (int r = 0; r < 4; r++)
                    C[(size_t)(row0 + r) * N + col] = f2b(acc[i][j][r]);
            }
        }
    }
}

// ------ GEMM2: 64x128 tile, BK=64, counted-vmcnt pipeline (proven r8) ------
__global__ __launch_bounds__(256) void gemm_bt2(const U16* __restrict__ A,
                                                const U16* __restrict__ Bt,
                                                const float* __restrict__ bias,
                                                float* __restrict__ C,
                                                int M, int N, int K) {
    __shared__ __align__(16) U16 As[2][64 * 64];
    __shared__ __align__(16) U16 Bs[2][128 * 64];
    const int m0 = blockIdx.y * 64, n0 = blockIdx.x * 128;
    const int t = threadIdx.x;
    const int wave = t >> 6, lane = t & 63, l15 = lane & 15, quad = lane >> 4;
    const int wm = (wave >> 1) * 32, wn = (wave & 1) * 64;

    f32x4 acc[2][4];
#pragma unroll
    for (int i = 0; i < 2; i++)
#pragma unroll
        for (int j = 0; j < 4; j++)
            acc[i][j] = (f32x4){0.f, 0.f, 0.f, 0.f};

    const int cA0 = t, cA1 = 256 + t;
    const int srA0 = cA0 >> 3, soA0 = (cA0 & 7) ^ (srA0 & 7);
    const int srA1 = cA1 >> 3, soA1 = (cA1 & 7) ^ (srA1 & 7);
    const U16* AgA0 = A + (size_t)(m0 + srA0) * K + soA0 * 8;
    const U16* AgA1 = A + (size_t)(m0 + srA1) * K + soA1 * 8;
    const int cB0 = t, cB1 = 256 + t, cB2 = 512 + t, cB3 = 768 + t;
    const int srB0 = cB0 >> 3, soB0 = (cB0 & 7) ^ (srB0 & 7);
    const int srB1 = cB1 >> 3, soB1 = (cB1 & 7) ^ (srB1 & 7);
    const int srB2 = cB2 >> 3, soB2 = (cB2 & 7) ^ (srB2 & 7);
    const int srB3 = cB3 >> 3, soB3 = (cB3 & 7) ^ (srB3 & 7);
    const U16* BgB0 = Bt + (size_t)(n0 + srB0) * K + soB0 * 8;
    const U16* BgB1 = Bt + (size_t)(n0 + srB1) * K + soB1 * 8;
    const U16* BgB2 = Bt + (size_t)(n0 + srB2) * K + soB2 * 8;
    const U16* BgB3 = Bt + (size_t)(n0 + srB3) * K + soB3 * 8;

    auto stAf = [&](int kt, U16* d) {               // 2 loads
        gld16(AgA0 + kt * 64, d + cA0 * 8);
        gld16(AgA1 + kt * 64, d + cA1 * 8);
    };
    auto stBf = [&](int kt, U16* d) {               // 4 loads
        gld16(BgB0 + kt * 64, d + cB0 * 8);
        gld16(BgB1 + kt * 64, d + cB1 * 8);
        gld16(BgB2 + kt * 64, d + cB2 * 8);
        gld16(BgB3 + kt * 64, d + cB3 * 8);
    };

    const int as0 = (quad ^ (l15 & 7)) * 8;
    const int as1 = ((4 + quad) ^ (l15 & 7)) * 8;
    const int nk = K >> 6;                          // 16

    auto ktile = [&](const U16* Ac, const U16* Bc, U16* An, U16* Bn, int kt) {
        const bool nx = (kt + 1) < nk;
        if (nx) {
            stAf(kt + 1, An);
            asm volatile("s_waitcnt vmcnt(2)" ::: "memory");
        } else {
            asm volatile("s_waitcnt vmcnt(0)" ::: "memory");
        }
        __builtin_amdgcn_s_barrier();
        asm volatile("" ::: "memory");
        bf16x8 af[2][2], bfr[4][2];
#pragma unroll
        for (int i = 0; i < 2; i++) {
            af[i][0] = *(const bf16x8*)&Ac[(wm + i * 16 + l15) * 64 + as0];
            af[i][1] = *(const bf16x8*)&Ac[(wm + i * 16 + l15) * 64 + as1];
        }
#pragma unroll
        for (int j = 0; j < 4; j++) {
            bfr[j][0] = *(const bf16x8*)&Bc[(wn + j * 16 + l15) * 64 + as0];
            bfr[j][1] = *(const bf16x8*)&Bc[(wn + j * 16 + l15) * 64 + as1];
        }
        if (nx) stBf(kt + 1, Bn);
        __builtin_amdgcn_s_setprio(1);
#pragma unroll
        for (int i = 0; i < 2; i++)
#pragma unroll
            for (int j = 0; j < 4; j++) {
                acc[i][j] = __builtin_amdgcn_mfma_f32_16x16x32_bf16(af[i][0], bfr[j][0], acc[i][j], 0, 0, 0);
                acc[i][j] = __builtin_amdgcn_mfma_f32_16x16x32_bf16(af[i][1], bfr[j][1], acc[i][j], 0, 0, 0);
            }
        __builtin_amdgcn_s_setprio(0);
        asm volatile("" ::: "memory");
        __builtin_amdgcn_s_barrier();
        asm volatile("" ::: "memory");
    };

    stAf(0, &As[0][0]);
    stBf(0, &Bs[0][0]);
    asm volatile("s_waitcnt vmcnt(0)" ::: "memory");
    __builtin_amdgcn_s_barrier();
    asm volatile("" ::: "memory");

    for (int kt = 0; kt < nk; kt += 2) {
        ktile(&As[0][0], &Bs[0][0], &As[1][0], &Bs[1][0], kt);
        ktile(&As[1][0], &Bs[1][0], &As[0][0], &Bs[0][0], kt + 1);
    }

#pragma unroll
    for (int i = 0; i < 2; i++) {
#pragma unroll
        for (int j = 0; j < 4; j++) {
            int col = n0 + wn + j * 16 + l15;
            float bv = bias[col];
#pragma unroll
            for (int r = 0; r < 4; r++) {
                int row = m0 + wm + i * 16 + quad * 4 + r;
                C[(size_t)row * N + col] = acc[i][j][r] + bv;
            }
        }
    }
}

// ---- MFMA flash attention, in-register softmax (r7-proven 54.7us version).
// r8 post-mortem: the chain-break reorder (QK1 hoist + split PV acc) raised
// VGPR 80->124 and REGRESSED 54.7->57us — the compiler's schedule was
// already overlapping; extra live state hurt. Reverted verbatim to r7.
__global__ __launch_bounds__(256) void attn_kernel(const U16* __restrict__ qkv,
                                                   const U16* __restrict__ vT,
                                                   U16* __restrict__ attn_out) {
    const int p = blockIdx.x;                    // 0..511
    const int xcd = p & 7;
    const int slot = p >> 3;                     // 0..63 within XCD
    const int bh = ((slot & 3) << 3) | xcd;      // bh & 7 == XCD id
    const int qt = slot >> 2;                    // 0..15, 128 q-rows per block
    const int b = bh >> 4, h = bh & 15;
    const int t = threadIdx.x;
    const int wave = t >> 6, lane = t & 63;
    const int l31 = lane & 31, hi = lane >> 5;
    const float sc2 = 0.125f * 1.44269504089f;  // scale * log2(e)

    __shared__ __align__(16) U16 Kt[2][64 * 64];    // [key][d-swizzled]
    __shared__ __align__(16) U16 Vt[2][64 * 64];    // [d][key-swizzled]

    const size_t base = (size_t)(b * 2048) * 3072;
    const U16* vTbh = vT + ((size_t)(b * 16 + h) * 64) * 2048;

    // Q fragments, pre-scaled by sc2 (softmax = exp2(S) with no per-iter mul)
    bf16x8 qf[4];
    {
        int qrow = qt * 128 + wave * 32 + l31;
        const U16* qp = qkv + base + (size_t)qrow * 3072 + h * 64 + hi * 8;
#pragma unroll
        for (int s = 0; s < 4; s++) {
            union { bf16x8 v; U16 u[8]; } a;
            a.v = *(const bf16x8*)&qp[s * 16];
#pragma unroll
            for (int e = 0; e < 8; e++) a.u[e] = f2b(b2f(a.u[e]) * sc2);
            qf[s] = a.v;
        }
    }

    float l4[4] = { 0.f, 0.f, 0.f, 0.f };
    f32x16 oacc[2];  // O^T[d][q]: d = db*32 + (reg&3)+8*(reg>>2)+4*hi, q=l31
#pragma unroll
    for (int db = 0; db < 2; db++)
#pragma unroll
        for (int r = 0; r < 16; r++)
            oacc[db][r] = 0.0f;

    const int c0 = t, c1 = 256 + t;
    const int row0 = c0 >> 3, oct0 = (c0 & 7) ^ (row0 & 7);
    const int row1 = c1 >> 3, oct1 = (c1 & 7) ^ (row1 & 7);

    gld16(&qkv[base + (size_t)row0 * 3072 + 1024 + h * 64 + oct0 * 8], &Kt[0][c0 * 8]);
    gld16(&qkv[base + (size_t)row1 * 3072 + 1024 + h * 64 + oct1 * 8], &Kt[0][c1 * 8]);
    gld16(&vTbh[(size_t)row0 * 2048 + oct0 * 8], &Vt[0][c0 * 8]);
    gld16(&vTbh[(size_t)row1 * 2048 + oct1 * 8], &Vt[0][c1 * 8]);
    __syncthreads();

    auto step = [&](const U16* KtC, const U16* VtC, U16* KtN, U16* VtN, int nt) {
        gld16(&qkv[base + (size_t)(nt * 64 + row0) * 3072 + 1024 + h * 64 + oct0 * 8], &KtN[c0 * 8]);
        gld16(&qkv[base + (size_t)(nt * 64 + row1) * 3072 + 1024 + h * 64 + oct1 * 8], &KtN[c1 * 8]);
        gld16(&vTbh[(size_t)row0 * 2048 + nt * 64 + oct0 * 8], &VtN[c0 * 8]);
        gld16(&vTbh[(size_t)row1 * 2048 + nt * 64 + oct1 * 8], &VtN[c1 * 8]);
#pragma unroll
        for (int kb = 0; kb < 2; kb++) {
            bf16x8 kf[4];
#pragma unroll
            for (int s = 0; s < 4; s++)
                kf[s] = *(const bf16x8*)&KtC[(kb * 32 + l31) * 64 +
                                             (((s * 2 + hi) ^ (l31 & 7)) * 8)];
            bf16x8 vfr[2][2];
#pragma unroll
            for (int db = 0; db < 2; db++)
#pragma unroll
                for (int s = 0; s < 2; s++)
                    vfr[db][s] = *(const bf16x8*)&VtC[(db * 32 + l31) * 64 +
                                                      (((kb * 4 + s * 2 + hi) ^ (l31 & 7)) * 8)];

            f32x16 st = {0.f, 0.f, 0.f, 0.f, 0.f, 0.f, 0.f, 0.f,
                         0.f, 0.f, 0.f, 0.f, 0.f, 0.f, 0.f, 0.f};
            __builtin_amdgcn_s_setprio(1);
#pragma unroll
            for (int s = 0; s < 4; s++)
                st = __builtin_amdgcn_mfma_f32_32x32x16_bf16(kf[s], qf[s], st, 0, 0, 0);
            __builtin_amdgcn_s_setprio(0);

            float pe[16];
#pragma unroll
            for (int r = 0; r < 16; r++) {
                pe[r] = __builtin_amdgcn_exp2f(st[r]);
                l4[r & 3] += pe[r];
            }

#pragma unroll
            for (int s = 0; s < 2; s++) {
                unsigned p01 = cvt_pk(pe[s * 8 + 0], pe[s * 8 + 1]);
                unsigned p23 = cvt_pk(pe[s * 8 + 2], pe[s * 8 + 3]);
                unsigned p45 = cvt_pk(pe[s * 8 + 4], pe[s * 8 + 5]);
                unsigned p67 = cvt_pk(pe[s * 8 + 6], pe[s * 8 + 7]);
                plswap(p01, p45);
                plswap(p23, p67);
                union { unsigned u[4]; bf16x8 v; } pw;
                pw.u[0] = p01; pw.u[1] = p23; pw.u[2] = p45; pw.u[3] = p67;
                __builtin_amdgcn_s_setprio(1);
#pragma unroll
                for (int db = 0; db < 2; db++)
                    oacc[db] = __builtin_amdgcn_mfma_f32_32x32x16_bf16(
                        vfr[db][s], pw.v, oacc[db], 0, 0, 0);
                __builtin_amdgcn_s_setprio(0);
            }
        }
        __syncthreads();
    };

    for (int kt2 = 0; kt2 < 16; kt2++) {
        step(&Kt[0][0], &Vt[0][0], &Kt[1][0], &Vt[1][0], 2 * kt2 + 1);
        step(&Kt[1][0], &Vt[1][0], &Kt[0][0], &Vt[0][0], (2 * kt2 + 2) & 31);
    }

    float l_acc = (l4[0] + l4[1]) + (l4[2] + l4[3]);
    float lt = l_acc + __shfl_xor(l_acc, 32);
    float inv = 1.0f / lt;
    int qrow = b * 2048 + qt * 128 + wave * 32 + l31;
#pragma unroll
    for (int db = 0; db < 2; db++) {
#pragma unroll
        for (int g = 0; g < 4; g++) {
            ushort4 stv;
            stv.x = f2b(oacc[db][g * 4 + 0] * inv);
            stv.y = f2b(oacc[db][g * 4 + 1] * inv);
            stv.z = f2b(oacc[db][g * 4 + 2] * inv);
            stv.w = f2b(oacc[db][g * 4 + 3] * inv);
            int col = h * 64 + db * 32 + g * 8 + hi * 4;
            *(ushort4*)&attn_out[(size_t)qrow * 1024 + col] = stv;
        }
    }
}

extern "C" void kernel_launch(void* const* d_in, const int* in_sizes, int n_in,
                              void* d_out, int out_size, void* d_ws, size_t ws_size,
                              hipStream_t stream) {
    (void)in_sizes; (void)n_in; (void)out_size; (void)ws_size;
    const float* x    = (const float*)d_in[0];
    const float* g    = (const float*)d_in[1];
    const float* be   = (const float*)d_in[2];
    const float* Wqkv = (const float*)d_in[3];
    const float* Wout = (const float*)d_in[4];
    const float* bout = (const float*)d_in[5];
    float* out = (float*)d_out;   // reference output dtype is fp32
    char* ws = (char*)d_ws;

    U16* xn   = (U16*)(ws);                          // 8 MB, reused as aout
    U16* qkv  = (U16*)(ws + (size_t)(8u  << 20));    // 24 MB (V third unused)
    U16* WqT  = (U16*)(ws + (size_t)(32u << 20));    // 6 MB
    U16* WoT  = (U16*)(ws + (size_t)(38u << 20));    // 2 MB
    U16* vT   = (U16*)(ws + (size_t)(40u << 20));    // 8 MB: V transposed
    U16* aout = xn;  // xn dead after GEMM1

    prep_kernel<<<8192, 256, 0, stream>>>(x, g, be, xn, Wqkv, WqT, Wout, WoT);
    gemm_g1<<<256, 512, 0, stream>>>(xn, WqT, qkv, vT, 4096, 3072, 1024);
    attn_kernel<<<512, 256, 0, stream>>>(qkv, vT, aout);
    gemm_bt2<<<dim3(1024 / 128, 4096 / 64), 256, 0, stream>>>(aout, WoT, bout, out, 4096, 1024, 1024);
}